// Round 1
// 29926.144 us; speedup vs baseline: 1.5709x; 1.5709x over previous
//
#include <hip/hip_runtime.h>
#include <hip/hip_bf16.h>
#include <math.h>

typedef __hip_bfloat16 bf;

#define B_ 8
#define S_ 512
#define H_ 768
#define L_ 12
#define NH_ 12
#define HD_ 64
#define FF_ 3072
#define NC_ 6
#define BS_ (B_ * S_)          // 4096 tokens
#define BSH_ ((size_t)BS_ * H_)

typedef __attribute__((ext_vector_type(8))) short s16x8;   // 8 bf16 (4 VGPRs)
typedef __attribute__((ext_vector_type(4))) float fx4;     // MFMA accumulator

// Runtime-dtype load: isbf chosen by detect_kernel from ln_emb_g's bit pattern.
__device__ __forceinline__ float LD(const void* p, size_t i, int isbf) {
    return isbf ? __bfloat162float(((const bf*)p)[i]) : ((const float*)p)[i];
}

// async global->LDS, 16B per lane. LDS dest must be wave-uniform base (+lane*16).
__device__ __forceinline__ void gload16(const void* g, void* l) {
    __builtin_amdgcn_global_load_lds(
        (const __attribute__((address_space(1))) void*)g,
        (__attribute__((address_space(3))) void*)l, 16, 0, 0);
}

// ---------------------------------------------------------------------------
// Detect float dtype of inputs: ln_emb_g is all ones.
// fp32: first word 0x3F800000. bf16: two 1.0 halves -> 0x3F803F80.
__global__ void detect_kernel(const unsigned int* __restrict__ g, int* __restrict__ flag) {
    if (threadIdx.x == 0 && blockIdx.x == 0)
        *flag = (g[0] == 0x3F800000u) ? 0 : 1;
}

// ---------------------------------------------------------------------------
// Relative-position sinusoid table: [129, 64]. Match numpy: fp64 math -> fp32.
__global__ void build_table_kernel(float* __restrict__ tab) {
    int idx = blockIdx.x * 256 + threadIdx.x;
    if (idx >= 129 * 64) return;
    int p = idx >> 6, d = idx & 63;
    double angle = (double)p / pow(10000.0, (double)(2 * (d / 2)) / 64.0);
    tab[idx] = (float)((d & 1) ? cos(angle) : sin(angle));
}

// ---------------------------------------------------------------------------
// Embedding sum (word + pos + type[0]) -> fp32
__global__ __launch_bounds__(256) void embed_kernel(
    const int* __restrict__ ids, const void* __restrict__ we,
    const void* __restrict__ pe, const void* __restrict__ te,
    float* __restrict__ y, const int* __restrict__ fl) {
    int isbf = *fl;
    int t = blockIdx.x;          // token 0..4095
    int s = t & (S_ - 1);
    int id = ids[t];
    size_t base = (size_t)t * H_;
    for (int c = threadIdx.x; c < H_; c += 256) {
        y[base + c] = LD(we, (size_t)id * H_ + c, isbf) +
                      LD(pe, (size_t)s * H_ + c, isbf) +
                      LD(te, c, isbf);
    }
}

// ---------------------------------------------------------------------------
// Mask bias: (1 - mask) * -10000
__global__ void maskbias_kernel(const int* __restrict__ mask, float* __restrict__ mb) {
    int t = blockIdx.x * 256 + threadIdx.x;
    if (t < BS_) mb[t] = (1.0f - (float)mask[t]) * -10000.0f;
}

// ---------------------------------------------------------------------------
// LayerNorm over H=768, one block (256 thr) per row. out = LN(a (+ resid)) * g + b
__global__ __launch_bounds__(256) void ln_kernel(
    float* out, const float* a, const float* resid,
    const void* __restrict__ g, const void* __restrict__ b, size_t goff,
    const int* __restrict__ fl) {
    __shared__ float part[256];
    int isbf = *fl;
    int tid = threadIdx.x;
    size_t base = (size_t)blockIdx.x * H_;
    float v0 = a[base + tid];
    float v1 = a[base + tid + 256];
    float v2 = a[base + tid + 512];
    if (resid) {
        v0 += resid[base + tid];
        v1 += resid[base + tid + 256];
        v2 += resid[base + tid + 512];
    }
    part[tid] = v0 + v1 + v2;
    __syncthreads();
    for (int off = 128; off > 0; off >>= 1) {
        if (tid < off) part[tid] += part[tid + off];
        __syncthreads();
    }
    float mu = part[0] * (1.0f / (float)H_);
    __syncthreads();
    float d0 = v0 - mu, d1 = v1 - mu, d2 = v2 - mu;
    part[tid] = d0 * d0 + d1 * d1 + d2 * d2;
    __syncthreads();
    for (int off = 128; off > 0; off >>= 1) {
        if (tid < off) part[tid] += part[tid + off];
        __syncthreads();
    }
    float var = part[0] * (1.0f / (float)H_);
    float rs = 1.0f / sqrtf(var + 1e-12f);
    out[base + tid]       = d0 * rs * LD(g, goff + tid, isbf)       + LD(b, goff + tid, isbf);
    out[base + tid + 256] = d1 * rs * LD(g, goff + tid + 256, isbf) + LD(b, goff + tid + 256, isbf);
    out[base + tid + 512] = d2 * rs * LD(g, goff + tid + 512, isbf) + LD(b, goff + tid + 512, isbf);
}

// ---------------------------------------------------------------------------
// Split fp32 -> bf16 (hi, lo) planes. n % 4 == 0. grid = n/1024.
__global__ __launch_bounds__(256) void split_kernel(const float* __restrict__ a,
    bf* __restrict__ hi, bf* __restrict__ lo, int n) {
    int i = (blockIdx.x * 256 + threadIdx.x) * 4;
    if (i >= n) return;
    const float4 v = *(const float4*)(a + i);
    float f[4] = {v.x, v.y, v.z, v.w};
    unsigned short hh[4], ll[4];
#pragma unroll
    for (int j = 0; j < 4; ++j) {
        bf h = __float2bfloat16(f[j]);
        bf l = __float2bfloat16(f[j] - __bfloat162float(h));
        hh[j] = *reinterpret_cast<unsigned short*>(&h);
        ll[j] = *reinterpret_cast<unsigned short*>(&l);
    }
    *(uint2*)(hi + i) = make_uint2(hh[0] | ((unsigned)hh[1] << 16), hh[2] | ((unsigned)hh[3] << 16));
    *(uint2*)(lo + i) = make_uint2(ll[0] | ((unsigned)ll[1] << 16), ll[2] | ((unsigned)ll[3] << 16));
}

// ---------------------------------------------------------------------------
// Transpose + split weights: W[K,N] (runtime dtype, woff elems) -> th,tl bf16 [N,K].
// grid = (K/32, N/32), 256 threads.
__global__ __launch_bounds__(256) void transpose_split_kernel(
    const void* __restrict__ W, size_t woff, bf* __restrict__ th, bf* __restrict__ tl,
    int K, int N, const int* __restrict__ fl) {
    __shared__ float s[32][33];
    const int isbf = *fl;
    const int tx = threadIdx.x & 31, ty = threadIdx.x >> 5;
    const int k0 = blockIdx.x * 32, n0 = blockIdx.y * 32;
#pragma unroll
    for (int i = 0; i < 4; ++i) {
        int k = k0 + ty + i * 8;
        s[ty + i * 8][tx] = LD(W, woff + (size_t)k * N + (n0 + tx), isbf);
    }
    __syncthreads();
#pragma unroll
    for (int i = 0; i < 4; ++i) {
        int n = n0 + ty + i * 8;
        float v = s[tx][ty + i * 8];
        bf h = __float2bfloat16(v);
        bf l = __float2bfloat16(v - __bfloat162float(h));
        th[(size_t)n * K + k0 + tx] = h;
        tl[(size_t)n * K + k0 + tx] = l;
    }
}

// ---------------------------------------------------------------------------
// Split-bf16 MFMA GEMM: C[M,N] = (Ah+Al)[M,K] @ (Bh+Bl)^T   (B planes are [N,K])
// + bias (runtime dtype), optional exact GELU; output either fp32 C or bf16 hi/lo
// planes (split_out, for the FFN hidden state).
// 128x128 tile, BK=32, 4 waves, 16x16x32 bf16 MFMA, 3 products (hh, hl, lh).
// M,N % 128 == 0, K % 32 == 0.
__global__ __launch_bounds__(256, 2) void mgemm_kernel(
    const bf* __restrict__ Ah, const bf* __restrict__ Al,
    const bf* __restrict__ Bh, const bf* __restrict__ Bl,
    const void* __restrict__ bias, size_t boff,
    float* __restrict__ C, bf* __restrict__ Chi, bf* __restrict__ Clo,
    int M, int N, int K, int act, int split_out, const int* __restrict__ fl) {
    (void)M;
    __shared__ __align__(16) unsigned short Ahs[128][32];
    __shared__ __align__(16) unsigned short Als[128][32];
    __shared__ __align__(16) unsigned short Bhs[128][32];
    __shared__ __align__(16) unsigned short Bls[128][32];
    const int tid  = threadIdx.x;
    const int lane = tid & 63;
    const int wid  = tid >> 6;         // 0..3
    const int wr   = wid >> 1, wc = wid & 1;
    const int m0 = blockIdx.y * 128, n0 = blockIdx.x * 128;
    const int srow = lane >> 2;        // 0..15 row within a 16-row staging group
    const int scol = (lane & 3) * 8;   // element offset (16B chunk)

    const fx4 fzero = {0.f, 0.f, 0.f, 0.f};
    fx4 acc[4][4];
#pragma unroll
    for (int i = 0; i < 4; ++i)
#pragma unroll
        for (int j = 0; j < 4; ++j) acc[i][j] = fzero;

    for (int k0 = 0; k0 < K; k0 += 32) {
        // stage 4 planes: each wave covers rows [wid*32, wid*32+32)
#pragma unroll
        for (int t = 0; t < 2; ++t) {
            const int r = wid * 32 + t * 16;
            const size_t ga = (size_t)(m0 + r + srow) * K + (k0 + scol);
            const size_t gb = (size_t)(n0 + r + srow) * K + (k0 + scol);
            gload16(Ah + ga, &Ahs[r][0]);
            gload16(Al + ga, &Als[r][0]);
            gload16(Bh + gb, &Bhs[r][0]);
            gload16(Bl + gb, &Bls[r][0]);
        }
        __syncthreads();   // compiler drains vmcnt before barrier

        const int fr = lane & 15;
        const int ko = (lane >> 4) * 8;
        s16x8 ah[4], al[4], bh[4], bl[4];
#pragma unroll
        for (int f = 0; f < 4; ++f) {
            ah[f] = *(const s16x8*)&Ahs[wr * 64 + f * 16 + fr][ko];
            al[f] = *(const s16x8*)&Als[wr * 64 + f * 16 + fr][ko];
            bh[f] = *(const s16x8*)&Bhs[wc * 64 + f * 16 + fr][ko];
            bl[f] = *(const s16x8*)&Bls[wc * 64 + f * 16 + fr][ko];
        }
#pragma unroll
        for (int im = 0; im < 4; ++im)
#pragma unroll
            for (int in = 0; in < 4; ++in) {
                acc[im][in] = __builtin_amdgcn_mfma_f32_16x16x32_bf16(ah[im], bh[in], acc[im][in], 0, 0, 0);
                acc[im][in] = __builtin_amdgcn_mfma_f32_16x16x32_bf16(ah[im], bl[in], acc[im][in], 0, 0, 0);
                acc[im][in] = __builtin_amdgcn_mfma_f32_16x16x32_bf16(al[im], bh[in], acc[im][in], 0, 0, 0);
            }
        __syncthreads();
    }

    // epilogue: C/D layout col = lane&15, row = (lane>>4)*4 + reg
    const int isbf = *fl;
    const int cr0 = m0 + wr * 64 + (lane >> 4) * 4;
    const int cc0 = n0 + wc * 64 + (lane & 15);
#pragma unroll
    for (int in = 0; in < 4; ++in) {
        const int col = cc0 + in * 16;
        const float bv = LD(bias, boff + col, isbf);
#pragma unroll
        for (int im = 0; im < 4; ++im) {
#pragma unroll
            for (int r = 0; r < 4; ++r) {
                const int row = cr0 + im * 16 + r;
                float v = acc[im][in][r] + bv;
                if (act) v = 0.5f * v * (1.0f + erff(v * 0.70710678118654752f));
                if (split_out) {
                    bf h = __float2bfloat16(v);
                    bf l = __float2bfloat16(v - __bfloat162float(h));
                    Chi[(size_t)row * N + col] = h;
                    Clo[(size_t)row * N + col] = l;
                } else {
                    C[(size_t)row * N + col] = v;
                }
            }
        }
    }
}

// ---------------------------------------------------------------------------
// Attention: one block per (b, h, i) query row. Fuses rel-pos into scores and ctx.
// (unchanged this round — next optimization target)
__global__ __launch_bounds__(256) void attn_kernel(
    const float* __restrict__ q, const float* __restrict__ k,
    const float* __restrict__ v, const float* __restrict__ tab,
    const float* __restrict__ mb, float* __restrict__ ctx) {
    __shared__ float tabs[129 * 64];
    __shared__ float sc[S_];
    __shared__ float tq[64];
    __shared__ float part[256];
    const int tid = threadIdx.x;
    int r = blockIdx.x;
    int i = r & (S_ - 1);
    int bh = r >> 9;
    int h = bh % NH_;
    int b = bh / NH_;

    for (int idx = tid; idx < 129 * 64; idx += 256) tabs[idx] = tab[idx];
    if (tid < 64) tq[tid] = q[((size_t)(b * S_ + i)) * H_ + h * 64 + tid];
    __syncthreads();

    float lmax = -1e30f;
#pragma unroll
    for (int rep = 0; rep < 2; ++rep) {
        int j = tid + rep * 256;
        const float* kp = k + ((size_t)(b * S_ + j)) * H_ + h * 64;
        int d0 = j - i;
        d0 = d0 < -64 ? -64 : (d0 > 64 ? 64 : d0);
        const float* tp = tabs + (d0 + 64) * 64;
        float s = 0.0f;
#pragma unroll 8
        for (int d = 0; d < 64; ++d) s += tq[d] * (kp[d] + tp[d]);
        s = s * 0.125f + mb[b * S_ + j];
        sc[j] = s;
        lmax = fmaxf(lmax, s);
    }
    part[tid] = lmax;
    __syncthreads();
    for (int off = 128; off > 0; off >>= 1) {
        if (tid < off) part[tid] = fmaxf(part[tid], part[tid + off]);
        __syncthreads();
    }
    float mx = part[0];
    __syncthreads();
    float lsum = 0.0f;
#pragma unroll
    for (int rep = 0; rep < 2; ++rep) {
        int j = tid + rep * 256;
        float e = expf(sc[j] - mx);
        sc[j] = e;
        lsum += e;
    }
    part[tid] = lsum;
    __syncthreads();
    for (int off = 128; off > 0; off >>= 1) {
        if (tid < off) part[tid] += part[tid + off];
        __syncthreads();
    }
    float inv = 1.0f / part[0];
    __syncthreads();

    int d = tid & 63, g = tid >> 6;
    float acc = 0.0f;
    for (int j = g * 128; j < g * 128 + 128; ++j) {
        int d0 = j - i;
        d0 = d0 < -64 ? -64 : (d0 > 64 ? 64 : d0);
        acc += sc[j] * (v[((size_t)(b * S_ + j)) * H_ + h * 64 + d] + tabs[(d0 + 64) * 64 + d]);
    }
    part[tid] = acc;
    __syncthreads();
    if (g == 0) {
        float s = part[d] + part[64 + d] + part[128 + d] + part[192 + d];
        ctx[((size_t)(b * S_ + i)) * H_ + h * 64 + d] = s * inv;
    }
}

// ---------------------------------------------------------------------------
// Pooler: pooled[b,n] = tanh(x[b,0,:] @ pW + pb). grid = B, 256 threads.
__global__ __launch_bounds__(256) void pool_kernel(
    const float* __restrict__ x, const void* __restrict__ pW,
    const void* __restrict__ pb, float* __restrict__ pooled,
    const int* __restrict__ fl) {
    int isbf = *fl;
    int b = blockIdx.x;
    const float* xr = x + (size_t)b * S_ * H_;  // row s=0
    for (int n = threadIdx.x; n < H_; n += 256) {
        float acc = LD(pb, n, isbf);
        for (int kx = 0; kx < H_; ++kx)
            acc += xr[kx] * LD(pW, (size_t)kx * H_ + n, isbf);
        pooled[b * H_ + n] = tanhf(acc);
    }
}

// seq_avg[b,c] = mean over s of x[b,s,c]. grid = B.
__global__ __launch_bounds__(256) void seqavg_kernel(
    const float* __restrict__ x, float* __restrict__ sa) {
    int b = blockIdx.x;
    for (int c = threadIdx.x; c < H_; c += 256) {
        float s = 0.0f;
        for (int j = 0; j < S_; ++j) s += x[((size_t)b * S_ + j) * H_ + c];
        sa[b * H_ + c] = s * (1.0f / (float)S_);
    }
}

// Final head: out[b,c] = [sa, pooled] @ cls_W + cls_b. 1 block, 64 threads.
__global__ void head_kernel(const float* __restrict__ sa, const float* __restrict__ pooled,
                            const void* __restrict__ cW, const void* __restrict__ cb,
                            void* __restrict__ out, const int* __restrict__ fl) {
    int isbf = *fl;
    int t = threadIdx.x;
    if (t >= B_ * NC_) return;
    int b = t / NC_, c = t % NC_;
    float acc = LD(cb, c, isbf);
    for (int kx = 0; kx < H_; ++kx)
        acc += sa[b * H_ + kx] * LD(cW, (size_t)kx * NC_ + c, isbf);
    for (int kx = 0; kx < H_; ++kx)
        acc += pooled[b * H_ + kx] * LD(cW, (size_t)(H_ + kx) * NC_ + c, isbf);
    if (isbf) ((bf*)out)[t] = __float2bfloat16(acc);
    else      ((float*)out)[t] = acc;
}

// ---------------------------------------------------------------------------
extern "C" void kernel_launch(void* const* d_in, const int* in_sizes, int n_in,
                              void* d_out, int out_size, void* d_ws, size_t ws_size,
                              hipStream_t stream) {
    (void)in_sizes; (void)n_in; (void)out_size; (void)ws_size;
    const int* ids   = (const int*)d_in[0];
    const int* amask = (const int*)d_in[1];
    const void* we  = d_in[2];
    const void* pe  = d_in[3];
    const void* te  = d_in[4];
    const void* lng = d_in[5];
    const void* lnb = d_in[6];
    const void* Wq  = d_in[7];
    const void* bq  = d_in[8];
    const void* Wk  = d_in[9];
    const void* bk  = d_in[10];
    const void* Wv  = d_in[11];
    const void* bv  = d_in[12];
    const void* Wo  = d_in[13];
    const void* bo  = d_in[14];
    const void* l1g = d_in[15];
    const void* l1b = d_in[16];
    const void* W1  = d_in[17];
    const void* b1  = d_in[18];
    const void* W2  = d_in[19];
    const void* b2  = d_in[20];
    const void* l2g = d_in[21];
    const void* l2b = d_in[22];
    const void* pW  = d_in[23];
    const void* pb  = d_in[24];
    const void* cW  = d_in[25];
    const void* cb  = d_in[26];

    // Workspace carve-up (~85 MB):
    //   x,r0..r3,z fp32 [4096,768] each.
    //   xh/xl (bf16 A-planes) alias z (dead whenever they're in use).
    //   hbh/hbl (bf16 FFN hidden planes, [4096,3072]) alias r0+r1 / r2+r3.
    //   wth/wtl: dedicated bf16 [3072,768]-max transposed weight planes.
    float* x    = (float*)d_ws;
    float* r0   = x  + BSH_;
    float* r1   = r0 + BSH_;
    float* r2   = r1 + BSH_;
    float* r3   = r2 + BSH_;
    float* z    = r3 + BSH_;
    float* tab  = z  + BSH_;               // [129,64]
    float* mb   = tab + 129 * 64;          // [4096]
    float* pool = mb + BS_;                // [8,768]
    float* sa   = pool + B_ * H_;          // [8,768]
    bf*    wth  = (bf*)(sa + B_ * H_);     // [N*K] max = H*FF
    bf*    wtl  = wth + (size_t)H_ * FF_;
    int*   flag = (int*)(wtl + (size_t)H_ * FF_);
    bf*    xh   = (bf*)z;                  // bf16 [4096,768]
    bf*    xl   = xh + BSH_;
    bf*    hbh  = (bf*)r0;                 // bf16 [4096,3072] spans r0+r1
    bf*    hbl  = (bf*)r2;                 // bf16 [4096,3072] spans r2+r3

    detect_kernel<<<1, 64, 0, stream>>>((const unsigned int*)lng, flag);
    build_table_kernel<<<(129 * 64 + 255) / 256, 256, 0, stream>>>(tab);
    maskbias_kernel<<<(BS_ + 255) / 256, 256, 0, stream>>>(amask, mb);
    embed_kernel<<<BS_, 256, 0, stream>>>(ids, we, pe, te, r0, flag);
    ln_kernel<<<BS_, 256, 0, stream>>>(x, r0, nullptr, lng, lnb, 0, flag);

    const int splitgrid = (int)(BSH_ / 1024);
    dim3 tpHH(H_ / 32, H_ / 32);     // W [H,H]
    dim3 tpHF(H_ / 32, FF_ / 32);    // W1 [H,FF]
    dim3 tpFH(FF_ / 32, H_ / 32);    // W2 [FF,H]
    dim3 gH(H_ / 128, BS_ / 128);    // mgemm N=768:  (6, 32)
    dim3 gF(FF_ / 128, BS_ / 128);   // mgemm N=3072: (24, 32)

    for (int l = 0; l < L_; ++l) {
        const size_t oHH = (size_t)l * H_ * H_;
        const size_t oH  = (size_t)l * H_;
        const size_t oHF = (size_t)l * H_ * FF_;
        const size_t oF  = (size_t)l * FF_;

        // ---- Q, K, V ----
        split_kernel<<<splitgrid, 256, 0, stream>>>(x, xh, xl, (int)BSH_);
        transpose_split_kernel<<<tpHH, 256, 0, stream>>>(Wq, oHH, wth, wtl, H_, H_, flag);
        mgemm_kernel<<<gH, 256, 0, stream>>>(xh, xl, wth, wtl, bq, oH,
                                             r1, nullptr, nullptr, BS_, H_, H_, 0, 0, flag);
        transpose_split_kernel<<<tpHH, 256, 0, stream>>>(Wk, oHH, wth, wtl, H_, H_, flag);
        mgemm_kernel<<<gH, 256, 0, stream>>>(xh, xl, wth, wtl, bk, oH,
                                             r2, nullptr, nullptr, BS_, H_, H_, 0, 0, flag);
        transpose_split_kernel<<<tpHH, 256, 0, stream>>>(Wv, oHH, wth, wtl, H_, H_, flag);
        mgemm_kernel<<<gH, 256, 0, stream>>>(xh, xl, wth, wtl, bv, oH,
                                             r3, nullptr, nullptr, BS_, H_, H_, 0, 0, flag);

        attn_kernel<<<B_ * NH_ * S_, 256, 0, stream>>>(r1, r2, r3, tab, mb, r0);

        // ---- output projection + LN1 ----
        split_kernel<<<splitgrid, 256, 0, stream>>>(r0, xh, xl, (int)BSH_);
        transpose_split_kernel<<<tpHH, 256, 0, stream>>>(Wo, oHH, wth, wtl, H_, H_, flag);
        mgemm_kernel<<<gH, 256, 0, stream>>>(xh, xl, wth, wtl, bo, oH,
                                             r1, nullptr, nullptr, BS_, H_, H_, 0, 0, flag);
        ln_kernel<<<BS_, 256, 0, stream>>>(x, r1, x, l1g, l1b, oH, flag);

        // ---- FFN ----
        split_kernel<<<splitgrid, 256, 0, stream>>>(x, xh, xl, (int)BSH_);
        transpose_split_kernel<<<tpHF, 256, 0, stream>>>(W1, oHF, wth, wtl, H_, FF_, flag);
        mgemm_kernel<<<gF, 256, 0, stream>>>(xh, xl, wth, wtl, b1, oF,
                                             nullptr, hbh, hbl, BS_, FF_, H_, 1, 1, flag);
        transpose_split_kernel<<<tpFH, 256, 0, stream>>>(W2, oHF, wth, wtl, FF_, H_, flag);
        mgemm_kernel<<<gH, 256, 0, stream>>>(hbh, hbl, wth, wtl, b2, oH,
                                             z, nullptr, nullptr, BS_, H_, FF_, 0, 0, flag);
        ln_kernel<<<BS_, 256, 0, stream>>>(x, z, x, l2g, l2b, oH, flag);
    }

    pool_kernel<<<B_, 256, 0, stream>>>(x, pW, pb, pool, flag);
    seqavg_kernel<<<B_, 256, 0, stream>>>(x, sa);
    head_kernel<<<1, 64, 0, stream>>>(sa, pool, cW, cb, d_out, flag);
}

// Round 2
// 14829.729 us; speedup vs baseline: 3.1700x; 2.0180x over previous
//
#include <hip/hip_runtime.h>
#include <hip/hip_bf16.h>
#include <math.h>

typedef __hip_bfloat16 bf;

#define B_ 8
#define S_ 512
#define H_ 768
#define L_ 12
#define NH_ 12
#define HD_ 64
#define FF_ 3072
#define NC_ 6
#define BS_ (B_ * S_)          // 4096 tokens
#define BSH_ ((size_t)BS_ * H_)
#define KAUG_ 672              // 512 (P) + 129 (arel) + 31 pad, %32==0
#define TAUG_ 160              // padded rel-bucket count for vaug columns

typedef __attribute__((ext_vector_type(8))) short s16x8;   // 8 bf16 (4 VGPRs)
typedef __attribute__((ext_vector_type(4))) float fx4;     // MFMA accumulator

// Runtime-dtype load: isbf chosen by detect_kernel from ln_emb_g's bit pattern.
__device__ __forceinline__ float LD(const void* p, size_t i, int isbf) {
    return isbf ? __bfloat162float(((const bf*)p)[i]) : ((const float*)p)[i];
}

// async global->LDS, 16B per lane. LDS dest must be wave-uniform base (+lane*16).
__device__ __forceinline__ void gload16(const void* g, void* l) {
    __builtin_amdgcn_global_load_lds(
        (const __attribute__((address_space(1))) void*)g,
        (__attribute__((address_space(3))) void*)l, 16, 0, 0);
}

// Swizzled fragment reads (both-sides XOR, rule 21): row-major LDS tiles whose
// 16B chunks were permuted at stage time by chunk ^= (row & mask).
__device__ __forceinline__ s16x8 ldfrag64(const unsigned short* base, int row, int chunk) {
    // row stride 64 ushorts (128 B, 8 chunks); key row&7
    return *(const s16x8*)((const char*)base + row * 128 + ((chunk ^ (row & 7)) << 4));
}
__device__ __forceinline__ s16x8 ldfrag32(const unsigned short* base, int row, int chunk) {
    // row stride 32 ushorts (64 B, 4 chunks); key row&3
    return *(const s16x8*)((const char*)base + row * 64 + ((chunk ^ (row & 3)) << 4));
}

// ---------------------------------------------------------------------------
__global__ void detect_kernel(const unsigned int* __restrict__ g, int* __restrict__ flag) {
    if (threadIdx.x == 0 && blockIdx.x == 0)
        *flag = (g[0] == 0x3F800000u) ? 0 : 1;
}

// ---------------------------------------------------------------------------
// Relative-position sinusoid table: [129, 64]. Match numpy: fp64 math -> fp32.
__global__ void build_table_kernel(float* __restrict__ tab) {
    int idx = blockIdx.x * 256 + threadIdx.x;
    if (idx >= 129 * 64) return;
    int p = idx >> 6, d = idx & 63;
    double angle = (double)p / pow(10000.0, (double)(2 * (d / 2)) / 64.0);
    tab[idx] = (float)((d & 1) ? cos(angle) : sin(angle));
}

// Transposed + split tab for the augmented-V build: tabT[d][t], t<129 real, rest 0.
__global__ void build_tabT_kernel(const float* __restrict__ tab,
                                  bf* __restrict__ th, bf* __restrict__ tl) {
    int idx = blockIdx.x * 256 + threadIdx.x;
    if (idx >= 64 * TAUG_) return;
    int d = idx / TAUG_, t = idx % TAUG_;
    float v = (t < 129) ? tab[t * 64 + d] : 0.0f;
    bf h = __float2bfloat16(v);
    th[idx] = h;
    tl[idx] = __float2bfloat16(v - __bfloat162float(h));
}

// ---------------------------------------------------------------------------
// Embedding sum (word + pos + type[0]) -> fp32
__global__ __launch_bounds__(256) void embed_kernel(
    const int* __restrict__ ids, const void* __restrict__ we,
    const void* __restrict__ pe, const void* __restrict__ te,
    float* __restrict__ y, const int* __restrict__ fl) {
    int isbf = *fl;
    int t = blockIdx.x;
    int s = t & (S_ - 1);
    int id = ids[t];
    size_t base = (size_t)t * H_;
    for (int c = threadIdx.x; c < H_; c += 256) {
        y[base + c] = LD(we, (size_t)id * H_ + c, isbf) +
                      LD(pe, (size_t)s * H_ + c, isbf) +
                      LD(te, c, isbf);
    }
}

// ---------------------------------------------------------------------------
__global__ void maskbias_kernel(const int* __restrict__ mask, float* __restrict__ mb) {
    int t = blockIdx.x * 256 + threadIdx.x;
    if (t < BS_) mb[t] = (1.0f - (float)mask[t]) * -10000.0f;
}

// ---------------------------------------------------------------------------
// LayerNorm over H=768, one block (256 thr) per row. out = LN(a (+ resid)) * g + b
__global__ __launch_bounds__(256) void ln_kernel(
    float* out, const float* a, const float* resid,
    const void* __restrict__ g, const void* __restrict__ b, size_t goff,
    const int* __restrict__ fl) {
    __shared__ float part[256];
    int isbf = *fl;
    int tid = threadIdx.x;
    size_t base = (size_t)blockIdx.x * H_;
    float v0 = a[base + tid];
    float v1 = a[base + tid + 256];
    float v2 = a[base + tid + 512];
    if (resid) {
        v0 += resid[base + tid];
        v1 += resid[base + tid + 256];
        v2 += resid[base + tid + 512];
    }
    part[tid] = v0 + v1 + v2;
    __syncthreads();
    for (int off = 128; off > 0; off >>= 1) {
        if (tid < off) part[tid] += part[tid + off];
        __syncthreads();
    }
    float mu = part[0] * (1.0f / (float)H_);
    __syncthreads();
    float d0 = v0 - mu, d1 = v1 - mu, d2 = v2 - mu;
    part[tid] = d0 * d0 + d1 * d1 + d2 * d2;
    __syncthreads();
    for (int off = 128; off > 0; off >>= 1) {
        if (tid < off) part[tid] += part[tid + off];
        __syncthreads();
    }
    float var = part[0] * (1.0f / (float)H_);
    float rs = 1.0f / sqrtf(var + 1e-12f);
    out[base + tid]       = d0 * rs * LD(g, goff + tid, isbf)       + LD(b, goff + tid, isbf);
    out[base + tid + 256] = d1 * rs * LD(g, goff + tid + 256, isbf) + LD(b, goff + tid + 256, isbf);
    out[base + tid + 512] = d2 * rs * LD(g, goff + tid + 512, isbf) + LD(b, goff + tid + 512, isbf);
}

// ---------------------------------------------------------------------------
// Split fp32 -> bf16 (hi, lo) planes. n % 4 == 0. grid = n/1024.
__global__ __launch_bounds__(256) void split_kernel(const float* __restrict__ a,
    bf* __restrict__ hi, bf* __restrict__ lo, int n) {
    int i = (blockIdx.x * 256 + threadIdx.x) * 4;
    if (i >= n) return;
    const float4 v = *(const float4*)(a + i);
    float f[4] = {v.x, v.y, v.z, v.w};
    unsigned short hh[4], ll[4];
#pragma unroll
    for (int j = 0; j < 4; ++j) {
        bf h = __float2bfloat16(f[j]);
        bf l = __float2bfloat16(f[j] - __bfloat162float(h));
        hh[j] = *reinterpret_cast<unsigned short*>(&h);
        ll[j] = *reinterpret_cast<unsigned short*>(&l);
    }
    *(uint2*)(hi + i) = make_uint2(hh[0] | ((unsigned)hh[1] << 16), hh[2] | ((unsigned)hh[3] << 16));
    *(uint2*)(lo + i) = make_uint2(ll[0] | ((unsigned)ll[1] << 16), ll[2] | ((unsigned)ll[3] << 16));
}

// ---------------------------------------------------------------------------
// Transpose + split weights: W[K,N] (runtime dtype, woff elems) -> th,tl bf16 [N,K].
__global__ __launch_bounds__(256) void transpose_split_kernel(
    const void* __restrict__ W, size_t woff, bf* __restrict__ th, bf* __restrict__ tl,
    int K, int N, const int* __restrict__ fl) {
    __shared__ float s[32][33];
    const int isbf = *fl;
    const int tx = threadIdx.x & 31, ty = threadIdx.x >> 5;
    const int k0 = blockIdx.x * 32, n0 = blockIdx.y * 32;
#pragma unroll
    for (int i = 0; i < 4; ++i) {
        int k = k0 + ty + i * 8;
        s[ty + i * 8][tx] = LD(W, woff + (size_t)k * N + (n0 + tx), isbf);
    }
    __syncthreads();
#pragma unroll
    for (int i = 0; i < 4; ++i) {
        int n = n0 + ty + i * 8;
        float v = s[tx][ty + i * 8];
        bf h = __float2bfloat16(v);
        bf l = __float2bfloat16(v - __bfloat162float(h));
        th[(size_t)n * K + k0 + tx] = h;
        tl[(size_t)n * K + k0 + tx] = l;
    }
}

// ---------------------------------------------------------------------------
// Split-bf16 MFMA GEMM (3 products): C[M,N] = (Ah+Al)[M,K] @ (Bh+Bl)^T, B planes [N,K].
// 128x128 tile, BK=32, 4 waves. Output fp32 C or bf16 hi/lo planes.
__global__ __launch_bounds__(256, 2) void mgemm_kernel(
    const bf* __restrict__ Ah, const bf* __restrict__ Al,
    const bf* __restrict__ Bh, const bf* __restrict__ Bl,
    const void* __restrict__ bias, size_t boff,
    float* __restrict__ C, bf* __restrict__ Chi, bf* __restrict__ Clo,
    int M, int N, int K, int act, int split_out, const int* __restrict__ fl) {
    (void)M;
    __shared__ __align__(16) unsigned short Ahs[128][32];
    __shared__ __align__(16) unsigned short Als[128][32];
    __shared__ __align__(16) unsigned short Bhs[128][32];
    __shared__ __align__(16) unsigned short Bls[128][32];
    const int tid  = threadIdx.x;
    const int lane = tid & 63;
    const int wid  = tid >> 6;
    const int wr   = wid >> 1, wc = wid & 1;
    const int m0 = blockIdx.y * 128, n0 = blockIdx.x * 128;
    const int srow = lane >> 2;
    const int scol = (lane & 3) * 8;

    const fx4 fzero = {0.f, 0.f, 0.f, 0.f};
    fx4 acc[4][4];
#pragma unroll
    for (int i = 0; i < 4; ++i)
#pragma unroll
        for (int j = 0; j < 4; ++j) acc[i][j] = fzero;

    for (int k0 = 0; k0 < K; k0 += 32) {
#pragma unroll
        for (int t = 0; t < 2; ++t) {
            const int r = wid * 32 + t * 16;
            const size_t ga = (size_t)(m0 + r + srow) * K + (k0 + scol);
            const size_t gb = (size_t)(n0 + r + srow) * K + (k0 + scol);
            gload16(Ah + ga, &Ahs[r][0]);
            gload16(Al + ga, &Als[r][0]);
            gload16(Bh + gb, &Bhs[r][0]);
            gload16(Bl + gb, &Bls[r][0]);
        }
        __syncthreads();

        const int fr = lane & 15;
        const int ko = (lane >> 4) * 8;
        s16x8 ah[4], al[4], bh[4], bl[4];
#pragma unroll
        for (int f = 0; f < 4; ++f) {
            ah[f] = *(const s16x8*)&Ahs[wr * 64 + f * 16 + fr][ko];
            al[f] = *(const s16x8*)&Als[wr * 64 + f * 16 + fr][ko];
            bh[f] = *(const s16x8*)&Bhs[wc * 64 + f * 16 + fr][ko];
            bl[f] = *(const s16x8*)&Bls[wc * 64 + f * 16 + fr][ko];
        }
#pragma unroll
        for (int im = 0; im < 4; ++im)
#pragma unroll
            for (int in = 0; in < 4; ++in) {
                acc[im][in] = __builtin_amdgcn_mfma_f32_16x16x32_bf16(ah[im], bh[in], acc[im][in], 0, 0, 0);
                acc[im][in] = __builtin_amdgcn_mfma_f32_16x16x32_bf16(ah[im], bl[in], acc[im][in], 0, 0, 0);
                acc[im][in] = __builtin_amdgcn_mfma_f32_16x16x32_bf16(al[im], bh[in], acc[im][in], 0, 0, 0);
            }
        __syncthreads();
    }

    const int isbf = *fl;
    const int cr0 = m0 + wr * 64 + (lane >> 4) * 4;
    const int cc0 = n0 + wc * 64 + (lane & 15);
#pragma unroll
    for (int in = 0; in < 4; ++in) {
        const int col = cc0 + in * 16;
        const float bv = LD(bias, boff + col, isbf);
#pragma unroll
        for (int im = 0; im < 4; ++im) {
#pragma unroll
            for (int r = 0; r < 4; ++r) {
                const int row = cr0 + im * 16 + r;
                float v = acc[im][in][r] + bv;
                if (act) v = 0.5f * v * (1.0f + erff(v * 0.70710678118654752f));
                if (split_out) {
                    bf h = __float2bfloat16(v);
                    bf l = __float2bfloat16(v - __bfloat162float(h));
                    Chi[(size_t)row * N + col] = h;
                    Clo[(size_t)row * N + col] = l;
                } else {
                    C[(size_t)row * N + col] = v;
                }
            }
        }
    }
}

// ---------------------------------------------------------------------------
// QK^T for one batch b (arg): scores[h,i,j] raw (no scale/rel/mask).
// grid (jt=4, it=4, h=12), 256 thr, split-bf16 3-product MFMA. K=64 in one stage.
__global__ __launch_bounds__(256, 2) void qk_kernel(
    const bf* __restrict__ qh, const bf* __restrict__ ql,
    const bf* __restrict__ kh, const bf* __restrict__ kl,
    float* __restrict__ sc, int b) {
    __shared__ __align__(16) unsigned short Qh[128][64];
    __shared__ __align__(16) unsigned short Ql_[128][64];
    __shared__ __align__(16) unsigned short Kh[128][64];
    __shared__ __align__(16) unsigned short Kl[128][64];
    const int tid = threadIdx.x, lane = tid & 63, wv = tid >> 6;
    const int j0 = blockIdx.x * 128, i0 = blockIdx.y * 128, h = blockIdx.z;
    const int srow = lane >> 3;                    // 0..7
    const int schunk = (lane & 7) ^ (srow & 7);    // pre-swizzled source chunk
#pragma unroll
    for (int t = 0; t < 4; ++t) {
        const int r = wv * 32 + t * 8;
        const size_t ga = (size_t)(b * S_ + i0 + r + srow) * H_ + h * 64 + schunk * 8;
        const size_t gb = (size_t)(b * S_ + j0 + r + srow) * H_ + h * 64 + schunk * 8;
        gload16(qh + ga, &Qh[r][0]);
        gload16(ql + ga, &Ql_[r][0]);
        gload16(kh + gb, &Kh[r][0]);
        gload16(kl + gb, &Kl[r][0]);
    }
    __syncthreads();
    const int fr = lane & 15, g = lane >> 4;
    const int wr = wv >> 1, wc = wv & 1;
    const fx4 fz = {0.f, 0.f, 0.f, 0.f};
    fx4 acc[4][4];
#pragma unroll
    for (int i = 0; i < 4; ++i)
#pragma unroll
        for (int j = 0; j < 4; ++j) acc[i][j] = fz;
#pragma unroll
    for (int ks = 0; ks < 2; ++ks) {
        s16x8 ah[4], al[4], bh[4], bl[4];
#pragma unroll
        for (int m = 0; m < 4; ++m) {
            const int row = wr * 64 + m * 16 + fr;
            ah[m] = ldfrag64(&Qh[0][0], row, ks * 4 + g);
            al[m] = ldfrag64(&Ql_[0][0], row, ks * 4 + g);
        }
#pragma unroll
        for (int n = 0; n < 4; ++n) {
            const int row = wc * 64 + n * 16 + fr;
            bh[n] = ldfrag64(&Kh[0][0], row, ks * 4 + g);
            bl[n] = ldfrag64(&Kl[0][0], row, ks * 4 + g);
        }
#pragma unroll
        for (int m = 0; m < 4; ++m)
#pragma unroll
            for (int n = 0; n < 4; ++n) {
                acc[m][n] = __builtin_amdgcn_mfma_f32_16x16x32_bf16(ah[m], bh[n], acc[m][n], 0, 0, 0);
                acc[m][n] = __builtin_amdgcn_mfma_f32_16x16x32_bf16(ah[m], bl[n], acc[m][n], 0, 0, 0);
                acc[m][n] = __builtin_amdgcn_mfma_f32_16x16x32_bf16(al[m], bh[n], acc[m][n], 0, 0, 0);
            }
    }
    const int rr = (lane >> 4) * 4, cc = lane & 15;
#pragma unroll
    for (int m = 0; m < 4; ++m)
#pragma unroll
        for (int n = 0; n < 4; ++n)
#pragma unroll
            for (int r = 0; r < 4; ++r) {
                const int ii = i0 + wr * 64 + m * 16 + rr + r;
                const int jj = j0 + wc * 64 + n * 16 + cc;
                sc[((size_t)h * S_ + ii) * S_ + jj] = acc[m][n][r];
            }
}

// ---------------------------------------------------------------------------
// Per-row softmax with rel-pos: one block per (i, h). Computes qrel on the fly
// from a transposed tab tile (conflict-free), applies scale+mask, softmax,
// 129-bucket arel sums, and writes the augmented P row (split bf16):
// cols [0,512) = probs, [512,641) = arel, [641,672) = 0.
__global__ __launch_bounds__(256) void smrel_kernel(
    const float* __restrict__ scores, const bf* __restrict__ qh, const bf* __restrict__ ql,
    const float* __restrict__ tab, const float* __restrict__ mb,
    bf* __restrict__ pah, bf* __restrict__ pal, int b) {
    __shared__ float tabT[64][132];
    __shared__ float sc[S_];
    __shared__ float red[256];
    __shared__ float qrow[64];
    __shared__ float qrelS[132];
    __shared__ float bkt[2];
    const int tid = threadIdx.x;
    const int i = blockIdx.x, h = blockIdx.y;

    for (int idx = tid; idx < 129 * 64; idx += 256) {
        int t = idx >> 6, d = idx & 63;
        tabT[d][t] = tab[idx];
    }
    if (tid < 64) {
        size_t a = (size_t)(b * S_ + i) * H_ + h * 64 + tid;
        qrow[tid] = __bfloat162float(qh[a]) + __bfloat162float(ql[a]);
    }
    __syncthreads();
    if (tid < 129) {
        float s = 0.0f;
        for (int d = 0; d < 64; ++d) s += qrow[d] * tabT[d][tid];
        qrelS[tid] = s;
    }
    __syncthreads();

    float lmax = -1e30f;
#pragma unroll
    for (int rep = 0; rep < 2; ++rep) {
        int j = tid + rep * 256;
        int t = j - i; t = t < -64 ? -64 : (t > 64 ? 64 : t);
        float s = (scores[((size_t)h * S_ + i) * S_ + j] + qrelS[t + 64]) * 0.125f
                  + mb[b * S_ + j];
        sc[j] = s;
        lmax = fmaxf(lmax, s);
    }
    red[tid] = lmax; __syncthreads();
    for (int off = 128; off > 0; off >>= 1) {
        if (tid < off) red[tid] = fmaxf(red[tid], red[tid + off]);
        __syncthreads();
    }
    float mx = red[0]; __syncthreads();
    float lsum = 0.0f;
#pragma unroll
    for (int rep = 0; rep < 2; ++rep) {
        int j = tid + rep * 256;
        float e = expf(sc[j] - mx);
        sc[j] = e;
        lsum += e;
    }
    red[tid] = lsum; __syncthreads();
    for (int off = 128; off > 0; off >>= 1) {
        if (tid < off) red[tid] += red[tid + off];
        __syncthreads();
    }
    const float inv = 1.0f / red[0];
    __syncthreads();

    // clipped-tail bucket sums (unnormalized; scale by inv at write)
    float s_lo = 0.0f, s_hi = 0.0f;
#pragma unroll
    for (int rep = 0; rep < 2; ++rep) {
        int j = tid + rep * 256;
        if (j <= i - 64) s_lo += sc[j];
        if (j >= i + 64) s_hi += sc[j];
    }
    red[tid] = s_lo; __syncthreads();
    for (int off = 128; off > 0; off >>= 1) {
        if (tid < off) red[tid] += red[tid + off];
        __syncthreads();
    }
    if (tid == 0) bkt[0] = red[0];
    __syncthreads();
    red[tid] = s_hi; __syncthreads();
    for (int off = 128; off > 0; off >>= 1) {
        if (tid < off) red[tid] += red[tid + off];
        __syncthreads();
    }
    if (tid == 0) bkt[1] = red[0];
    __syncthreads();

    const size_t rowbase = (size_t)(h * S_ + i) * KAUG_;
#pragma unroll
    for (int rep = 0; rep < 2; ++rep) {
        int j = tid + rep * 256;
        float v = sc[j] * inv;
        bf hh = __float2bfloat16(v);
        pah[rowbase + j] = hh;
        pal[rowbase + j] = __float2bfloat16(v - __bfloat162float(hh));
    }
    if (tid < TAUG_) {
        float v = 0.0f;
        if (tid == 0)        v = bkt[0] * inv;
        else if (tid == 128) v = bkt[1] * inv;
        else if (tid < 128) {
            int j = i + tid - 64;
            v = (j >= 0 && j < S_) ? sc[j] * inv : 0.0f;
        }
        bf hh = __float2bfloat16(v);
        pah[rowbase + 512 + tid] = hh;
        pal[rowbase + 512 + tid] = __float2bfloat16(v - __bfloat162float(hh));
    }
}

// ---------------------------------------------------------------------------
// Build augmented V^T for one batch: vaug[pl][h][d][0..511]=V^T, [512..671]=tabT pad.
// grid (h=12, plane=2), 256 thr, LDS transpose.
__global__ __launch_bounds__(256) void vaug_kernel(
    const bf* __restrict__ vh, const bf* __restrict__ vl,
    const bf* __restrict__ tabTh, const bf* __restrict__ tabTl,
    bf* __restrict__ vah, bf* __restrict__ val_, int b) {
    __shared__ unsigned short tile[64][71];
    const int h = blockIdx.x, pl = blockIdx.y;
    const bf* src  = pl ? vl : vh;
    bf*       dst  = pl ? val_ : vah;
    const bf* tsrc = pl ? tabTl : tabTh;
    const int tid = threadIdx.x;
    for (int j0 = 0; j0 < S_; j0 += 64) {
        for (int idx = tid; idx < 4096; idx += 256) {
            int jj = idx >> 6, d = idx & 63;
            tile[jj][d] = *(const unsigned short*)&src[(size_t)(b * S_ + j0 + jj) * H_ + h * 64 + d];
        }
        __syncthreads();
        for (int idx = tid; idx < 4096; idx += 256) {
            int d = idx >> 6, jj = idx & 63;
            *(unsigned short*)&dst[(size_t)(h * 64 + d) * KAUG_ + j0 + jj] = tile[jj][d];
        }
        __syncthreads();
    }
    for (int idx = tid; idx < 64 * TAUG_; idx += 256) {
        int d = idx / TAUG_, t = idx % TAUG_;
        *(unsigned short*)&dst[(size_t)(h * 64 + d) * KAUG_ + 512 + t] =
            *(const unsigned short*)&tsrc[idx];
    }
}

// ---------------------------------------------------------------------------
// ctx = [P|arel] @ [V; tab]: per-batch, grid (h=12, it=4). M=128, N=64, K=672.
// Split-bf16 3-product MFMA, output fp32 ctx in token-major [B,S,H] layout.
__global__ __launch_bounds__(256, 2) void pv_kernel(
    const bf* __restrict__ pah, const bf* __restrict__ pal,
    const bf* __restrict__ vah, const bf* __restrict__ val_,
    float* __restrict__ ctx, int b) {
    __shared__ __align__(16) unsigned short Ah[128][32];
    __shared__ __align__(16) unsigned short Al[128][32];
    __shared__ __align__(16) unsigned short Bh[64][32];
    __shared__ __align__(16) unsigned short Bl[64][32];
    const int tid = threadIdx.x, lane = tid & 63, wv = tid >> 6;
    const int h = blockIdx.x, i0 = blockIdx.y * 128;
    const int srow = lane >> 2;                    // 0..15
    const int schunk = (lane & 3) ^ (srow & 3);
    const fx4 fz = {0.f, 0.f, 0.f, 0.f};
    fx4 acc[2][4];
#pragma unroll
    for (int m = 0; m < 2; ++m)
#pragma unroll
        for (int n = 0; n < 4; ++n) acc[m][n] = fz;

    for (int k0 = 0; k0 < KAUG_; k0 += 32) {
#pragma unroll
        for (int t = 0; t < 2; ++t) {
            const int r = wv * 32 + t * 16;
            const size_t ga = (size_t)(h * S_ + i0 + r + srow) * KAUG_ + k0 + schunk * 8;
            gload16(pah + ga, &Ah[r][0]);
            gload16(pal + ga, &Al[r][0]);
        }
        {
            const int r = wv * 16;
            const size_t gb = (size_t)(h * 64 + r + srow) * KAUG_ + k0 + schunk * 8;
            gload16(vah + gb, &Bh[r][0]);
            gload16(val_ + gb, &Bl[r][0]);
        }
        __syncthreads();
        const int fr = lane & 15, g = lane >> 4;
        s16x8 a_h[2], a_l[2], b_h[4], b_l[4];
#pragma unroll
        for (int m = 0; m < 2; ++m) {
            const int row = wv * 32 + m * 16 + fr;
            a_h[m] = ldfrag32(&Ah[0][0], row, g);
            a_l[m] = ldfrag32(&Al[0][0], row, g);
        }
#pragma unroll
        for (int n = 0; n < 4; ++n) {
            const int row = n * 16 + fr;
            b_h[n] = ldfrag32(&Bh[0][0], row, g);
            b_l[n] = ldfrag32(&Bl[0][0], row, g);
        }
#pragma unroll
        for (int m = 0; m < 2; ++m)
#pragma unroll
            for (int n = 0; n < 4; ++n) {
                acc[m][n] = __builtin_amdgcn_mfma_f32_16x16x32_bf16(a_h[m], b_h[n], acc[m][n], 0, 0, 0);
                acc[m][n] = __builtin_amdgcn_mfma_f32_16x16x32_bf16(a_h[m], b_l[n], acc[m][n], 0, 0, 0);
                acc[m][n] = __builtin_amdgcn_mfma_f32_16x16x32_bf16(a_l[m], b_h[n], acc[m][n], 0, 0, 0);
            }
        __syncthreads();
    }
    const int rr = (lane >> 4) * 4, cc = lane & 15;
#pragma unroll
    for (int m = 0; m < 2; ++m)
#pragma unroll
        for (int n = 0; n < 4; ++n)
#pragma unroll
            for (int r = 0; r < 4; ++r) {
                const int row = i0 + wv * 32 + m * 16 + rr + r;
                const int d = n * 16 + cc;
                ctx[(size_t)(b * S_ + row) * H_ + h * 64 + d] = acc[m][n][r];
            }
}

// ---------------------------------------------------------------------------
__global__ __launch_bounds__(256) void pool_kernel(
    const float* __restrict__ x, const void* __restrict__ pW,
    const void* __restrict__ pb, float* __restrict__ pooled,
    const int* __restrict__ fl) {
    int isbf = *fl;
    int b = blockIdx.x;
    const float* xr = x + (size_t)b * S_ * H_;
    for (int n = threadIdx.x; n < H_; n += 256) {
        float acc = LD(pb, n, isbf);
        for (int kx = 0; kx < H_; ++kx)
            acc += xr[kx] * LD(pW, (size_t)kx * H_ + n, isbf);
        pooled[b * H_ + n] = tanhf(acc);
    }
}

__global__ __launch_bounds__(256) void seqavg_kernel(
    const float* __restrict__ x, float* __restrict__ sa) {
    int b = blockIdx.x;
    for (int c = threadIdx.x; c < H_; c += 256) {
        float s = 0.0f;
        for (int j = 0; j < S_; ++j) s += x[((size_t)b * S_ + j) * H_ + c];
        sa[b * H_ + c] = s * (1.0f / (float)S_);
    }
}

__global__ void head_kernel(const float* __restrict__ sa, const float* __restrict__ pooled,
                            const void* __restrict__ cW, const void* __restrict__ cb,
                            void* __restrict__ out, const int* __restrict__ fl) {
    int isbf = *fl;
    int t = threadIdx.x;
    if (t >= B_ * NC_) return;
    int b = t / NC_, c = t % NC_;
    float acc = LD(cb, c, isbf);
    for (int kx = 0; kx < H_; ++kx)
        acc += sa[b * H_ + kx] * LD(cW, (size_t)kx * NC_ + c, isbf);
    for (int kx = 0; kx < H_; ++kx)
        acc += pooled[b * H_ + kx] * LD(cW, (size_t)(H_ + kx) * NC_ + c, isbf);
    if (isbf) ((bf*)out)[t] = __float2bfloat16(acc);
    else      ((float*)out)[t] = acc;
}

// ---------------------------------------------------------------------------
extern "C" void kernel_launch(void* const* d_in, const int* in_sizes, int n_in,
                              void* d_out, int out_size, void* d_ws, size_t ws_size,
                              hipStream_t stream) {
    (void)in_sizes; (void)n_in; (void)out_size; (void)ws_size;
    const int* ids   = (const int*)d_in[0];
    const int* amask = (const int*)d_in[1];
    const void* we  = d_in[2];
    const void* pe  = d_in[3];
    const void* te  = d_in[4];
    const void* lng = d_in[5];
    const void* lnb = d_in[6];
    const void* Wq  = d_in[7];
    const void* bq  = d_in[8];
    const void* Wk  = d_in[9];
    const void* bk  = d_in[10];
    const void* Wv  = d_in[11];
    const void* bv  = d_in[12];
    const void* Wo  = d_in[13];
    const void* bo  = d_in[14];
    const void* l1g = d_in[15];
    const void* l1b = d_in[16];
    const void* W1  = d_in[17];
    const void* b1  = d_in[18];
    const void* W2  = d_in[19];
    const void* b2  = d_in[20];
    const void* l2g = d_in[21];
    const void* l2b = d_in[22];
    const void* pW  = d_in[23];
    const void* pb  = d_in[24];
    const void* cW  = d_in[25];
    const void* cb  = d_in[26];

    // Workspace carve-up (~104 MB):
    //   x, r0, r1f..r3f, z: fp32 [4096,768].
    //   r1f/r2f/r3f reinterpreted as q/k/v split-bf16 planes during attention;
    //   r1f doubles as Wo-output fp32 (q planes dead by then).
    //   z doubles as xh/xl split planes AND as per-batch score buffer [12,512,512].
    //   hbh/hbl (FFN hidden, bf16 [4096,3072]) alias r0+r1f / r2f+r3f.
    float* x    = (float*)d_ws;
    float* r0   = x   + BSH_;
    float* r1f  = r0  + BSH_;
    float* r2f  = r1f + BSH_;
    float* r3f  = r2f + BSH_;
    float* z    = r3f + BSH_;
    float* tab  = z   + BSH_;              // [129,64] fp32
    float* mb   = tab + 129 * 64;          // [4096]
    float* pool = mb + BS_;                // [8,768]
    float* sa   = pool + B_ * H_;          // [8,768]
    bf*    wth  = (bf*)(sa + B_ * H_);     // transposed weight planes, max H*FF
    bf*    wtl  = wth + (size_t)H_ * FF_;
    bf*    tabTh = wtl + (size_t)H_ * FF_; // [64,160] bf16
    bf*    tabTl = tabTh + 64 * TAUG_;
    bf*    pah  = tabTl + 64 * TAUG_;      // augmented P planes [12,512,672]
    bf*    pal  = pah + (size_t)NH_ * S_ * KAUG_;
    bf*    vah  = pal + (size_t)NH_ * S_ * KAUG_;   // augmented V^T [12,64,672]
    bf*    val_ = vah + (size_t)NH_ * 64 * KAUG_;
    int*   flag = (int*)(val_ + (size_t)NH_ * 64 * KAUG_);

    bf* qh  = (bf*)r1f; bf* qlp = qh  + BSH_;
    bf* khp = (bf*)r2f; bf* klp = khp + BSH_;
    bf* vhp = (bf*)r3f; bf* vlp = vhp + BSH_;
    bf* xh  = (bf*)z;   bf* xl  = xh  + BSH_;
    bf* hbh = (bf*)r0;                     // [4096,3072] spans r0+r1f
    bf* hbl = (bf*)r2f;                    // spans r2f+r3f

    detect_kernel<<<1, 64, 0, stream>>>((const unsigned int*)lng, flag);
    build_table_kernel<<<(129 * 64 + 255) / 256, 256, 0, stream>>>(tab);
    build_tabT_kernel<<<(64 * TAUG_ + 255) / 256, 256, 0, stream>>>(tab, tabTh, tabTl);
    maskbias_kernel<<<(BS_ + 255) / 256, 256, 0, stream>>>(amask, mb);
    embed_kernel<<<BS_, 256, 0, stream>>>(ids, we, pe, te, r0, flag);
    ln_kernel<<<BS_, 256, 0, stream>>>(x, r0, nullptr, lng, lnb, 0, flag);

    const int splitgrid = (int)(BSH_ / 1024);
    dim3 tpHH(H_ / 32, H_ / 32);
    dim3 tpHF(H_ / 32, FF_ / 32);
    dim3 tpFH(FF_ / 32, H_ / 32);
    dim3 gH(H_ / 128, BS_ / 128);
    dim3 gF(FF_ / 128, BS_ / 128);
    dim3 gQK(4, 4, NH_);
    dim3 gSM(S_, NH_);
    dim3 gPV(NH_, 4);
    dim3 gVA(NH_, 2);

    for (int l = 0; l < L_; ++l) {
        const size_t oHH = (size_t)l * H_ * H_;
        const size_t oH  = (size_t)l * H_;
        const size_t oHF = (size_t)l * H_ * FF_;
        const size_t oF  = (size_t)l * FF_;

        // ---- Q, K, V (split-bf16 outputs) ----
        split_kernel<<<splitgrid, 256, 0, stream>>>(x, xh, xl, (int)BSH_);
        transpose_split_kernel<<<tpHH, 256, 0, stream>>>(Wq, oHH, wth, wtl, H_, H_, flag);
        mgemm_kernel<<<gH, 256, 0, stream>>>(xh, xl, wth, wtl, bq, oH,
                                             nullptr, qh, qlp, BS_, H_, H_, 0, 1, flag);
        transpose_split_kernel<<<tpHH, 256, 0, stream>>>(Wk, oHH, wth, wtl, H_, H_, flag);
        mgemm_kernel<<<gH, 256, 0, stream>>>(xh, xl, wth, wtl, bk, oH,
                                             nullptr, khp, klp, BS_, H_, H_, 0, 1, flag);
        transpose_split_kernel<<<tpHH, 256, 0, stream>>>(Wv, oHH, wth, wtl, H_, H_, flag);
        mgemm_kernel<<<gH, 256, 0, stream>>>(xh, xl, wth, wtl, bv, oH,
                                             nullptr, vhp, vlp, BS_, H_, H_, 0, 1, flag);

        // ---- attention, chunked per batch (scores reuse z) ----
        for (int b = 0; b < B_; ++b) {
            vaug_kernel<<<gVA, 256, 0, stream>>>(vhp, vlp, tabTh, tabTl, vah, val_, b);
            qk_kernel<<<gQK, 256, 0, stream>>>(qh, qlp, khp, klp, z, b);
            smrel_kernel<<<gSM, 256, 0, stream>>>(z, qh, qlp, tab, mb, pah, pal, b);
            pv_kernel<<<gPV, 256, 0, stream>>>(pah, pal, vah, val_, r0, b);
        }

        // ---- output projection + LN1 ----
        split_kernel<<<splitgrid, 256, 0, stream>>>(r0, xh, xl, (int)BSH_);
        transpose_split_kernel<<<tpHH, 256, 0, stream>>>(Wo, oHH, wth, wtl, H_, H_, flag);
        mgemm_kernel<<<gH, 256, 0, stream>>>(xh, xl, wth, wtl, bo, oH,
                                             r1f, nullptr, nullptr, BS_, H_, H_, 0, 0, flag);
        ln_kernel<<<BS_, 256, 0, stream>>>(x, r1f, x, l1g, l1b, oH, flag);

        // ---- FFN ----
        split_kernel<<<splitgrid, 256, 0, stream>>>(x, xh, xl, (int)BSH_);
        transpose_split_kernel<<<tpHF, 256, 0, stream>>>(W1, oHF, wth, wtl, H_, FF_, flag);
        mgemm_kernel<<<gF, 256, 0, stream>>>(xh, xl, wth, wtl, b1, oF,
                                             nullptr, hbh, hbl, BS_, FF_, H_, 1, 1, flag);
        transpose_split_kernel<<<tpFH, 256, 0, stream>>>(W2, oHF, wth, wtl, FF_, H_, flag);
        mgemm_kernel<<<gH, 256, 0, stream>>>(hbh, hbl, wth, wtl, b2, oH,
                                             z, nullptr, nullptr, BS_, H_, FF_, 0, 0, flag);
        ln_kernel<<<BS_, 256, 0, stream>>>(x, z, x, l2g, l2b, oH, flag);
    }

    pool_kernel<<<B_, 256, 0, stream>>>(x, pW, pb, pool, flag);
    seqavg_kernel<<<B_, 256, 0, stream>>>(x, sa);
    head_kernel<<<1, 64, 0, stream>>>(sa, pool, cW, cb, d_out, flag);
}

// Round 3
// 7814.486 us; speedup vs baseline: 6.0158x; 1.8977x over previous
//
#include <hip/hip_runtime.h>
#include <hip/hip_bf16.h>
#include <math.h>

typedef __hip_bfloat16 bf;

#define B_ 8
#define S_ 512
#define H_ 768
#define L_ 12
#define NH_ 12
#define HD_ 64
#define FF_ 3072
#define NC_ 6
#define BS_ (B_ * S_)          // 4096 tokens
#define BSH_ ((size_t)BS_ * H_)
#define KAUG_ 672              // 512 (P) + 129 (arel) + 31 pad, %32==0
#define TAUG_ 160              // padded rel-bucket count for vaug columns
#define TPAD_ 144              // padded rel-bucket count for qrel rows

typedef __attribute__((ext_vector_type(8))) short s16x8;   // 8 bf16 (4 VGPRs)
typedef __attribute__((ext_vector_type(4))) float fx4;     // MFMA accumulator

// Runtime-dtype load: isbf chosen by detect_kernel from ln_emb_g's bit pattern.
__device__ __forceinline__ float LD(const void* p, size_t i, int isbf) {
    return isbf ? __bfloat162float(((const bf*)p)[i]) : ((const float*)p)[i];
}

// async global->LDS, 16B per lane. LDS dest must be wave-uniform base (+lane*16).
__device__ __forceinline__ void gload16(const void* g, void* l) {
    __builtin_amdgcn_global_load_lds(
        (const __attribute__((address_space(1))) void*)g,
        (__attribute__((address_space(3))) void*)l, 16, 0, 0);
}

// Swizzled fragment reads (both-sides XOR, rule 21): row-major LDS tiles whose
// 16B chunks were permuted at stage time by chunk ^= (row & mask).
__device__ __forceinline__ s16x8 ldfrag64(const unsigned short* base, int row, int chunk) {
    return *(const s16x8*)((const char*)base + row * 128 + ((chunk ^ (row & 7)) << 4));
}
__device__ __forceinline__ s16x8 ldfrag32(const unsigned short* base, int row, int chunk) {
    return *(const s16x8*)((const char*)base + row * 64 + ((chunk ^ (row & 3)) << 4));
}

__device__ __forceinline__ float wred_sum(float v) {
#pragma unroll
    for (int o = 32; o; o >>= 1) v += __shfl_xor(v, o, 64);
    return v;
}
__device__ __forceinline__ float wred_max(float v) {
#pragma unroll
    for (int o = 32; o; o >>= 1) v = fmaxf(v, __shfl_xor(v, o, 64));
    return v;
}

// ---------------------------------------------------------------------------
__global__ void detect_kernel(const unsigned int* __restrict__ g, int* __restrict__ flag) {
    if (threadIdx.x == 0 && blockIdx.x == 0)
        *flag = (g[0] == 0x3F800000u) ? 0 : 1;
}

// ---------------------------------------------------------------------------
// Relative-position sinusoid table: [129, 64]. Match numpy: fp64 math -> fp32.
__global__ void build_table_kernel(float* __restrict__ tab) {
    int idx = blockIdx.x * 256 + threadIdx.x;
    if (idx >= 129 * 64) return;
    int p = idx >> 6, d = idx & 63;
    double angle = (double)p / pow(10000.0, (double)(2 * (d / 2)) / 64.0);
    tab[idx] = (float)((d & 1) ? cos(angle) : sin(angle));
}

// Transposed + split tab for the augmented-V build: tabT[d][t], t<129 real, rest 0.
__global__ void build_tabT_kernel(const float* __restrict__ tab,
                                  bf* __restrict__ th, bf* __restrict__ tl) {
    int idx = blockIdx.x * 256 + threadIdx.x;
    if (idx >= 64 * TAUG_) return;
    int d = idx / TAUG_, t = idx % TAUG_;
    float v = (t < 129) ? tab[t * 64 + d] : 0.0f;
    bf h = __float2bfloat16(v);
    th[idx] = h;
    tl[idx] = __float2bfloat16(v - __bfloat162float(h));
}

// t-major split tab [144][64] for the qrel MFMA B-operand.
__global__ void build_tabS_kernel(const float* __restrict__ tab,
                                  bf* __restrict__ th, bf* __restrict__ tl) {
    int idx = blockIdx.x * 256 + threadIdx.x;
    if (idx >= TPAD_ * 64) return;
    int t = idx >> 6;
    float v = (t < 129) ? tab[idx] : 0.0f;
    bf h = __float2bfloat16(v);
    th[idx] = h;
    tl[idx] = __float2bfloat16(v - __bfloat162float(h));
}

// ---------------------------------------------------------------------------
// Embedding sum (word + pos + type[0]) -> fp32
__global__ __launch_bounds__(256) void embed_kernel(
    const int* __restrict__ ids, const void* __restrict__ we,
    const void* __restrict__ pe, const void* __restrict__ te,
    float* __restrict__ y, const int* __restrict__ fl) {
    int isbf = *fl;
    int t = blockIdx.x;
    int s = t & (S_ - 1);
    int id = ids[t];
    size_t base = (size_t)t * H_;
    for (int c = threadIdx.x; c < H_; c += 256) {
        y[base + c] = LD(we, (size_t)id * H_ + c, isbf) +
                      LD(pe, (size_t)s * H_ + c, isbf) +
                      LD(te, c, isbf);
    }
}

// ---------------------------------------------------------------------------
__global__ void maskbias_kernel(const int* __restrict__ mask, float* __restrict__ mb) {
    int t = blockIdx.x * 256 + threadIdx.x;
    if (t < BS_) mb[t] = (1.0f - (float)mask[t]) * -10000.0f;
}

// ---------------------------------------------------------------------------
// LayerNorm over H=768, one block (256 thr) per row. out = LN(a (+ resid)) * g + b
// Optionally also emits split-bf16 planes (ohi/olo) of the result.
__global__ __launch_bounds__(256) void ln_kernel(
    float* out, bf* ohi, bf* olo, const float* a, const float* resid,
    const void* __restrict__ g, const void* __restrict__ b, size_t goff,
    const int* __restrict__ fl) {
    __shared__ float part[256];
    int isbf = *fl;
    int tid = threadIdx.x;
    size_t base = (size_t)blockIdx.x * H_;
    float v0 = a[base + tid];
    float v1 = a[base + tid + 256];
    float v2 = a[base + tid + 512];
    if (resid) {
        v0 += resid[base + tid];
        v1 += resid[base + tid + 256];
        v2 += resid[base + tid + 512];
    }
    part[tid] = v0 + v1 + v2;
    __syncthreads();
    for (int off = 128; off > 0; off >>= 1) {
        if (tid < off) part[tid] += part[tid + off];
        __syncthreads();
    }
    float mu = part[0] * (1.0f / (float)H_);
    __syncthreads();
    float d0 = v0 - mu, d1 = v1 - mu, d2 = v2 - mu;
    part[tid] = d0 * d0 + d1 * d1 + d2 * d2;
    __syncthreads();
    for (int off = 128; off > 0; off >>= 1) {
        if (tid < off) part[tid] += part[tid + off];
        __syncthreads();
    }
    float var = part[0] * (1.0f / (float)H_);
    float rs = 1.0f / sqrtf(var + 1e-12f);
    float o0 = d0 * rs * LD(g, goff + tid, isbf)       + LD(b, goff + tid, isbf);
    float o1 = d1 * rs * LD(g, goff + tid + 256, isbf) + LD(b, goff + tid + 256, isbf);
    float o2 = d2 * rs * LD(g, goff + tid + 512, isbf) + LD(b, goff + tid + 512, isbf);
    out[base + tid]       = o0;
    out[base + tid + 256] = o1;
    out[base + tid + 512] = o2;
    if (ohi) {
        bf h0 = __float2bfloat16(o0), h1 = __float2bfloat16(o1), h2 = __float2bfloat16(o2);
        ohi[base + tid]       = h0;
        ohi[base + tid + 256] = h1;
        ohi[base + tid + 512] = h2;
        olo[base + tid]       = __float2bfloat16(o0 - __bfloat162float(h0));
        olo[base + tid + 256] = __float2bfloat16(o1 - __bfloat162float(h1));
        olo[base + tid + 512] = __float2bfloat16(o2 - __bfloat162float(h2));
    }
}

// ---------------------------------------------------------------------------
// Transpose + split weights: W[K,N] (runtime dtype, woff elems) -> th,tl bf16 [N,K].
__global__ __launch_bounds__(256) void transpose_split_kernel(
    const void* __restrict__ W, size_t woff, bf* __restrict__ th, bf* __restrict__ tl,
    int K, int N, const int* __restrict__ fl) {
    __shared__ float s[32][33];
    const int isbf = *fl;
    const int tx = threadIdx.x & 31, ty = threadIdx.x >> 5;
    const int k0 = blockIdx.x * 32, n0 = blockIdx.y * 32;
#pragma unroll
    for (int i = 0; i < 4; ++i) {
        int k = k0 + ty + i * 8;
        s[ty + i * 8][tx] = LD(W, woff + (size_t)k * N + (n0 + tx), isbf);
    }
    __syncthreads();
#pragma unroll
    for (int i = 0; i < 4; ++i) {
        int n = n0 + ty + i * 8;
        float v = s[tx][ty + i * 8];
        bf h = __float2bfloat16(v);
        bf l = __float2bfloat16(v - __bfloat162float(h));
        th[(size_t)n * K + k0 + tx] = h;
        tl[(size_t)n * K + k0 + tx] = l;
    }
}

// ---------------------------------------------------------------------------
// Split-bf16 MFMA GEMM (3 products): C[M,N] = (Ah+Al)[M,K] @ (Bh+Bl)^T, B planes [N,K].
// 128x128 tile, BK=32, 4 waves. Output fp32 C or bf16 hi/lo planes.
__global__ __launch_bounds__(256, 2) void mgemm_kernel(
    const bf* __restrict__ Ah, const bf* __restrict__ Al,
    const bf* __restrict__ Bh, const bf* __restrict__ Bl,
    const void* __restrict__ bias, size_t boff,
    float* __restrict__ C, bf* __restrict__ Chi, bf* __restrict__ Clo,
    int M, int N, int K, int act, int split_out, const int* __restrict__ fl) {
    (void)M;
    __shared__ __align__(16) unsigned short Ahs[128][32];
    __shared__ __align__(16) unsigned short Als[128][32];
    __shared__ __align__(16) unsigned short Bhs[128][32];
    __shared__ __align__(16) unsigned short Bls[128][32];
    const int tid  = threadIdx.x;
    const int lane = tid & 63;
    const int wid  = tid >> 6;
    const int wr   = wid >> 1, wc = wid & 1;
    const int m0 = blockIdx.y * 128, n0 = blockIdx.x * 128;
    const int srow = lane >> 2;
    const int scol = (lane & 3) * 8;

    const fx4 fzero = {0.f, 0.f, 0.f, 0.f};
    fx4 acc[4][4];
#pragma unroll
    for (int i = 0; i < 4; ++i)
#pragma unroll
        for (int j = 0; j < 4; ++j) acc[i][j] = fzero;

    for (int k0 = 0; k0 < K; k0 += 32) {
#pragma unroll
        for (int t = 0; t < 2; ++t) {
            const int r = wid * 32 + t * 16;
            const size_t ga = (size_t)(m0 + r + srow) * K + (k0 + scol);
            const size_t gb = (size_t)(n0 + r + srow) * K + (k0 + scol);
            gload16(Ah + ga, &Ahs[r][0]);
            gload16(Al + ga, &Als[r][0]);
            gload16(Bh + gb, &Bhs[r][0]);
            gload16(Bl + gb, &Bls[r][0]);
        }
        __syncthreads();

        const int fr = lane & 15;
        const int ko = (lane >> 4) * 8;
        s16x8 ah[4], al[4], bh[4], bl[4];
#pragma unroll
        for (int f = 0; f < 4; ++f) {
            ah[f] = *(const s16x8*)&Ahs[wr * 64 + f * 16 + fr][ko];
            al[f] = *(const s16x8*)&Als[wr * 64 + f * 16 + fr][ko];
            bh[f] = *(const s16x8*)&Bhs[wc * 64 + f * 16 + fr][ko];
            bl[f] = *(const s16x8*)&Bls[wc * 64 + f * 16 + fr][ko];
        }
#pragma unroll
        for (int im = 0; im < 4; ++im)
#pragma unroll
            for (int in = 0; in < 4; ++in) {
                acc[im][in] = __builtin_amdgcn_mfma_f32_16x16x32_bf16(ah[im], bh[in], acc[im][in], 0, 0, 0);
                acc[im][in] = __builtin_amdgcn_mfma_f32_16x16x32_bf16(ah[im], bl[in], acc[im][in], 0, 0, 0);
                acc[im][in] = __builtin_amdgcn_mfma_f32_16x16x32_bf16(al[im], bh[in], acc[im][in], 0, 0, 0);
            }
        __syncthreads();
    }

    const int isbf = *fl;
    const int cr0 = m0 + wr * 64 + (lane >> 4) * 4;
    const int cc0 = n0 + wc * 64 + (lane & 15);
#pragma unroll
    for (int in = 0; in < 4; ++in) {
        const int col = cc0 + in * 16;
        const float bv = LD(bias, boff + col, isbf);
#pragma unroll
        for (int im = 0; im < 4; ++im) {
#pragma unroll
            for (int r = 0; r < 4; ++r) {
                const int row = cr0 + im * 16 + r;
                float v = acc[im][in][r] + bv;
                if (act) v = 0.5f * v * (1.0f + erff(v * 0.70710678118654752f));
                if (split_out) {
                    bf h = __float2bfloat16(v);
                    bf l = __float2bfloat16(v - __bfloat162float(h));
                    Chi[(size_t)row * N + col] = h;
                    Clo[(size_t)row * N + col] = l;
                } else {
                    C[(size_t)row * N + col] = v;
                }
            }
        }
    }
}

// ---------------------------------------------------------------------------
// qrel[bb,h,i,t] = q[b,i,h,:] . tab[t,:]  (3-product split-bf16 MFMA).
// grid (CB*S/128, NH, 3), 256 thr. tabS planes are [144][64] t-major.
__global__ __launch_bounds__(256) void qrel_kernel(
    const bf* __restrict__ qh, const bf* __restrict__ ql,
    const bf* __restrict__ tabSh, const bf* __restrict__ tabSl,
    float* __restrict__ qrel, int b0) {
    const int tid = threadIdx.x, lane = tid & 63, wv = tid >> 6;
    const int rbase = blockIdx.x * 128;      // chunk-local token row base
    const int h = blockIdx.y;
    const int t0 = blockIdx.z * 48;
    const int fr = lane & 15, ko = (lane >> 4) * 8;
    const fx4 fz = {0.f, 0.f, 0.f, 0.f};
    fx4 acc[2][3];
#pragma unroll
    for (int m = 0; m < 2; ++m)
#pragma unroll
        for (int n = 0; n < 3; ++n) acc[m][n] = fz;
#pragma unroll
    for (int ks = 0; ks < 2; ++ks) {
        s16x8 a_h[2], a_l[2], b_h[3], b_l[3];
#pragma unroll
        for (int m = 0; m < 2; ++m) {
            const int row = rbase + wv * 32 + m * 16 + fr;
            const size_t ga = ((size_t)(b0 * S_) + row) * H_ + h * 64 + ks * 32 + ko;
            a_h[m] = *(const s16x8*)(qh + ga);
            a_l[m] = *(const s16x8*)(ql + ga);
        }
#pragma unroll
        for (int n = 0; n < 3; ++n) {
            const int trow = t0 + n * 16 + fr;
            const size_t gb = (size_t)trow * 64 + ks * 32 + ko;
            b_h[n] = *(const s16x8*)(tabSh + gb);
            b_l[n] = *(const s16x8*)(tabSl + gb);
        }
#pragma unroll
        for (int m = 0; m < 2; ++m)
#pragma unroll
            for (int n = 0; n < 3; ++n) {
                acc[m][n] = __builtin_amdgcn_mfma_f32_16x16x32_bf16(a_h[m], b_h[n], acc[m][n], 0, 0, 0);
                acc[m][n] = __builtin_amdgcn_mfma_f32_16x16x32_bf16(a_h[m], b_l[n], acc[m][n], 0, 0, 0);
                acc[m][n] = __builtin_amdgcn_mfma_f32_16x16x32_bf16(a_l[m], b_h[n], acc[m][n], 0, 0, 0);
            }
    }
    const int rr = (lane >> 4) * 4, cc = lane & 15;
#pragma unroll
    for (int m = 0; m < 2; ++m)
#pragma unroll
        for (int n = 0; n < 3; ++n)
#pragma unroll
            for (int r = 0; r < 3 + 1; ++r) {
                const int row = rbase + wv * 32 + m * 16 + rr + r;
                const int t = t0 + n * 16 + cc;
                const int bb = row >> 9, ii = row & (S_ - 1);
                qrel[(((size_t)bb * NH_ + h) * S_ + ii) * TPAD_ + t] = acc[m][n][r];
            }
}

// ---------------------------------------------------------------------------
// QK^T: scores[bb,h,i,j] raw. grid (jt=4, it=4, NH*CB), 256 thr.
__global__ __launch_bounds__(256, 2) void qk_kernel(
    const bf* __restrict__ qh, const bf* __restrict__ ql,
    const bf* __restrict__ kh, const bf* __restrict__ kl,
    float* __restrict__ sc, int b0) {
    __shared__ __align__(16) unsigned short Qh[128][64];
    __shared__ __align__(16) unsigned short Ql_[128][64];
    __shared__ __align__(16) unsigned short Kh[128][64];
    __shared__ __align__(16) unsigned short Kl[128][64];
    const int tid = threadIdx.x, lane = tid & 63, wv = tid >> 6;
    const int j0 = blockIdx.x * 128, i0 = blockIdx.y * 128;
    const int h = blockIdx.z % NH_, bb = blockIdx.z / NH_;
    const int b = b0 + bb;
    const int srow = lane >> 3;
    const int schunk = (lane & 7) ^ (srow & 7);
#pragma unroll
    for (int t = 0; t < 4; ++t) {
        const int r = wv * 32 + t * 8;
        const size_t ga = (size_t)(b * S_ + i0 + r + srow) * H_ + h * 64 + schunk * 8;
        const size_t gb = (size_t)(b * S_ + j0 + r + srow) * H_ + h * 64 + schunk * 8;
        gload16(qh + ga, &Qh[r][0]);
        gload16(ql + ga, &Ql_[r][0]);
        gload16(kh + gb, &Kh[r][0]);
        gload16(kl + gb, &Kl[r][0]);
    }
    __syncthreads();
    const int fr = lane & 15, g = lane >> 4;
    const int wr = wv >> 1, wc = wv & 1;
    const fx4 fz = {0.f, 0.f, 0.f, 0.f};
    fx4 acc[4][4];
#pragma unroll
    for (int i = 0; i < 4; ++i)
#pragma unroll
        for (int j = 0; j < 4; ++j) acc[i][j] = fz;
#pragma unroll
    for (int ks = 0; ks < 2; ++ks) {
        s16x8 ah[4], al[4], bh[4], bl[4];
#pragma unroll
        for (int m = 0; m < 4; ++m) {
            const int row = wr * 64 + m * 16 + fr;
            ah[m] = ldfrag64(&Qh[0][0], row, ks * 4 + g);
            al[m] = ldfrag64(&Ql_[0][0], row, ks * 4 + g);
        }
#pragma unroll
        for (int n = 0; n < 4; ++n) {
            const int row = wc * 64 + n * 16 + fr;
            bh[n] = ldfrag64(&Kh[0][0], row, ks * 4 + g);
            bl[n] = ldfrag64(&Kl[0][0], row, ks * 4 + g);
        }
#pragma unroll
        for (int m = 0; m < 4; ++m)
#pragma unroll
            for (int n = 0; n < 4; ++n) {
                acc[m][n] = __builtin_amdgcn_mfma_f32_16x16x32_bf16(ah[m], bh[n], acc[m][n], 0, 0, 0);
                acc[m][n] = __builtin_amdgcn_mfma_f32_16x16x32_bf16(ah[m], bl[n], acc[m][n], 0, 0, 0);
                acc[m][n] = __builtin_amdgcn_mfma_f32_16x16x32_bf16(al[m], bh[n], acc[m][n], 0, 0, 0);
            }
    }
    const int rr = (lane >> 4) * 4, cc = lane & 15;
#pragma unroll
    for (int m = 0; m < 4; ++m)
#pragma unroll
        for (int n = 0; n < 4; ++n)
#pragma unroll
            for (int r = 0; r < 4; ++r) {
                const int ii = i0 + wr * 64 + m * 16 + rr + r;
                const int jj = j0 + wc * 64 + n * 16 + cc;
                sc[(((size_t)bb * NH_ + h) * S_ + ii) * S_ + jj] = acc[m][n][r];
            }
}

// ---------------------------------------------------------------------------
// Wave-per-row softmax + augmented-P emit. grid (S/4, NH, CB), 256 thr (4 waves).
// Each wave owns one (i,h,bb) row: barrier-free shuffle reductions.
__global__ __launch_bounds__(256) void smrel_kernel(
    const float* __restrict__ scores, const float* __restrict__ qrel,
    const float* __restrict__ mb,
    bf* __restrict__ pah, bf* __restrict__ pal, int b0) {
    const int lane = threadIdx.x & 63;
    const int wv = threadIdx.x >> 6;
    const int i = blockIdx.x * 4 + wv;
    const int h = blockIdx.y, bb = blockIdx.z;
    const int b = b0 + bb;
    const size_t srow = ((size_t)bb * NH_ + h) * S_ + i;
    const size_t qbase = srow * TPAD_;
    const float mbias = mb[b * S_ + lane] * 0.0f + 0.0f; (void)mbias;  // per-j below

    float s[8];
    float lmax = -1e30f;
#pragma unroll
    for (int rep = 0; rep < 8; ++rep) {
        const int j = lane + rep * 64;
        int t = j - i; t = t < -64 ? -64 : (t > 64 ? 64 : t);
        float v = (scores[srow * S_ + j] + qrel[qbase + t + 64]) * 0.125f + mb[b * S_ + j];
        s[rep] = v;
        lmax = fmaxf(lmax, v);
    }
    const float mx = wred_max(lmax);
    float lsum = 0.0f;
#pragma unroll
    for (int rep = 0; rep < 8; ++rep) {
        s[rep] = expf(s[rep] - mx);
        lsum += s[rep];
    }
    const float inv = 1.0f / wred_sum(lsum);

    const size_t rowbase = srow * KAUG_;
    // zero the arel section first (wave-synchronous ordering makes this safe)
#pragma unroll
    for (int e = 0; e < 3; ++e) {
        const int t = lane + e * 64;
        if (t < TAUG_) {
            pah[rowbase + 512 + t] = __float2bfloat16(0.0f);
            pal[rowbase + 512 + t] = __float2bfloat16(0.0f);
        }
    }
    float s_lo = 0.0f, s_hi = 0.0f;
#pragma unroll
    for (int rep = 0; rep < 8; ++rep) {
        const int j = lane + rep * 64;
        const float v = s[rep] * inv;
        bf hh = __float2bfloat16(v);
        pah[rowbase + j] = hh;
        pal[rowbase + j] = __float2bfloat16(v - __bfloat162float(hh));
        const int d = j - i;
        if (d <= -64) s_lo += s[rep];
        else if (d >= 64) s_hi += s[rep];
        else {  // interior bucket: unique j per t
            pah[rowbase + 512 + d + 64] = hh;
            pal[rowbase + 512 + d + 64] = __float2bfloat16(v - __bfloat162float(hh));
        }
    }
    s_lo = wred_sum(s_lo);
    s_hi = wred_sum(s_hi);
    if (lane == 0) {
        float v0 = s_lo * inv;
        bf h0 = __float2bfloat16(v0);
        pah[rowbase + 512] = h0;
        pal[rowbase + 512] = __float2bfloat16(v0 - __bfloat162float(h0));
        float v1 = s_hi * inv;
        bf h1 = __float2bfloat16(v1);
        pah[rowbase + 512 + 128] = h1;
        pal[rowbase + 512 + 128] = __float2bfloat16(v1 - __bfloat162float(h1));
    }
}

// ---------------------------------------------------------------------------
// Build augmented V^T: vaug[bb][h][d][0..511]=V^T, [512..671]=tabT pad.
// grid (NH, 2, CB), 256 thr.
__global__ __launch_bounds__(256) void vaug_kernel(
    const bf* __restrict__ vh, const bf* __restrict__ vl,
    const bf* __restrict__ tabTh, const bf* __restrict__ tabTl,
    bf* __restrict__ vah, bf* __restrict__ val_, int b0) {
    __shared__ unsigned short tile[64][71];
    const int h = blockIdx.x, pl = blockIdx.y, bb = blockIdx.z;
    const int b = b0 + bb;
    const bf* src  = pl ? vl : vh;
    bf*       dst  = pl ? val_ : vah;
    const bf* tsrc = pl ? tabTl : tabTh;
    const int tid = threadIdx.x;
    const size_t dbase = ((size_t)bb * NH_ + h) * 64;
    for (int j0 = 0; j0 < S_; j0 += 64) {
        for (int idx = tid; idx < 4096; idx += 256) {
            int jj = idx >> 6, d = idx & 63;
            tile[jj][d] = *(const unsigned short*)&src[(size_t)(b * S_ + j0 + jj) * H_ + h * 64 + d];
        }
        __syncthreads();
        for (int idx = tid; idx < 4096; idx += 256) {
            int d = idx >> 6, jj = idx & 63;
            *(unsigned short*)&dst[(dbase + d) * KAUG_ + j0 + jj] = tile[jj][d];
        }
        __syncthreads();
    }
    for (int idx = tid; idx < 64 * TAUG_; idx += 256) {
        int d = idx / TAUG_, t = idx % TAUG_;
        *(unsigned short*)&dst[(dbase + d) * KAUG_ + 512 + t] =
            *(const unsigned short*)&tsrc[idx];
    }
}

// ---------------------------------------------------------------------------
// ctx = [P|arel] @ [V; tab]: grid (NH, 4, CB). M=128, N=64, K=672.
// Output: split-bf16 context planes (feeds the Wo GEMM directly).
__global__ __launch_bounds__(256, 2) void pv_kernel(
    const bf* __restrict__ pah, const bf* __restrict__ pal,
    const bf* __restrict__ vah, const bf* __restrict__ val_,
    bf* __restrict__ ch, bf* __restrict__ cl, int b0) {
    __shared__ __align__(16) unsigned short Ah[128][32];
    __shared__ __align__(16) unsigned short Al[128][32];
    __shared__ __align__(16) unsigned short Bh[64][32];
    __shared__ __align__(16) unsigned short Bl[64][32];
    const int tid = threadIdx.x, lane = tid & 63, wv = tid >> 6;
    const int h = blockIdx.x, i0 = blockIdx.y * 128, bb = blockIdx.z;
    const int b = b0 + bb;
    const int srow = lane >> 2;
    const int schunk = (lane & 3) ^ (srow & 3);
    const fx4 fz = {0.f, 0.f, 0.f, 0.f};
    fx4 acc[2][4];
#pragma unroll
    for (int m = 0; m < 2; ++m)
#pragma unroll
        for (int n = 0; n < 4; ++n) acc[m][n] = fz;

    for (int k0 = 0; k0 < KAUG_; k0 += 32) {
#pragma unroll
        for (int t = 0; t < 2; ++t) {
            const int r = wv * 32 + t * 16;
            const size_t ga = (((size_t)bb * NH_ + h) * S_ + i0 + r + srow) * KAUG_ + k0 + schunk * 8;
            gload16(pah + ga, &Ah[r][0]);
            gload16(pal + ga, &Al[r][0]);
        }
        {
            const int r = wv * 16;
            const size_t gb = (((size_t)bb * NH_ + h) * 64 + r + srow) * KAUG_ + k0 + schunk * 8;
            gload16(vah + gb, &Bh[r][0]);
            gload16(val_ + gb, &Bl[r][0]);
        }
        __syncthreads();
        const int fr = lane & 15, g = lane >> 4;
        s16x8 a_h[2], a_l[2], b_h[4], b_l[4];
#pragma unroll
        for (int m = 0; m < 2; ++m) {
            const int row = wv * 32 + m * 16 + fr;
            a_h[m] = ldfrag32(&Ah[0][0], row, g);
            a_l[m] = ldfrag32(&Al[0][0], row, g);
        }
#pragma unroll
        for (int n = 0; n < 4; ++n) {
            const int row = n * 16 + fr;
            b_h[n] = ldfrag32(&Bh[0][0], row, g);
            b_l[n] = ldfrag32(&Bl[0][0], row, g);
        }
#pragma unroll
        for (int m = 0; m < 2; ++m)
#pragma unroll
            for (int n = 0; n < 4; ++n) {
                acc[m][n] = __builtin_amdgcn_mfma_f32_16x16x32_bf16(a_h[m], b_h[n], acc[m][n], 0, 0, 0);
                acc[m][n] = __builtin_amdgcn_mfma_f32_16x16x32_bf16(a_h[m], b_l[n], acc[m][n], 0, 0, 0);
                acc[m][n] = __builtin_amdgcn_mfma_f32_16x16x32_bf16(a_l[m], b_h[n], acc[m][n], 0, 0, 0);
            }
        __syncthreads();
    }
    const int rr = (lane >> 4) * 4, cc = lane & 15;
#pragma unroll
    for (int m = 0; m < 2; ++m)
#pragma unroll
        for (int n = 0; n < 4; ++n)
#pragma unroll
            for (int r = 0; r < 4; ++r) {
                const int row = i0 + wv * 32 + m * 16 + rr + r;
                const int d = n * 16 + cc;
                const float v = acc[m][n][r];
                bf hh = __float2bfloat16(v);
                const size_t o = (size_t)(b * S_ + row) * H_ + h * 64 + d;
                ch[o] = hh;
                cl[o] = __float2bfloat16(v - __bfloat162float(hh));
            }
}

// ---------------------------------------------------------------------------
__global__ __launch_bounds__(256) void pool_kernel(
    const float* __restrict__ x, const void* __restrict__ pW,
    const void* __restrict__ pb, float* __restrict__ pooled,
    const int* __restrict__ fl) {
    int isbf = *fl;
    int b = blockIdx.x;
    const float* xr = x + (size_t)b * S_ * H_;
    for (int n = threadIdx.x; n < H_; n += 256) {
        float acc = LD(pb, n, isbf);
        for (int kx = 0; kx < H_; ++kx)
            acc += xr[kx] * LD(pW, (size_t)kx * H_ + n, isbf);
        pooled[b * H_ + n] = tanhf(acc);
    }
}

__global__ __launch_bounds__(256) void seqavg_kernel(
    const float* __restrict__ x, float* __restrict__ sa) {
    int b = blockIdx.x;
    for (int c = threadIdx.x; c < H_; c += 256) {
        float s = 0.0f;
        for (int j = 0; j < S_; ++j) s += x[((size_t)b * S_ + j) * H_ + c];
        sa[b * H_ + c] = s * (1.0f / (float)S_);
    }
}

__global__ void head_kernel(const float* __restrict__ sa, const float* __restrict__ pooled,
                            const void* __restrict__ cW, const void* __restrict__ cb,
                            void* __restrict__ out, const int* __restrict__ fl) {
    int isbf = *fl;
    int t = threadIdx.x;
    if (t >= B_ * NC_) return;
    int b = t / NC_, c = t % NC_;
    float acc = LD(cb, c, isbf);
    for (int kx = 0; kx < H_; ++kx)
        acc += sa[b * H_ + kx] * LD(cW, (size_t)kx * NC_ + c, isbf);
    for (int kx = 0; kx < H_; ++kx)
        acc += pooled[b * H_ + kx] * LD(cW, (size_t)(H_ + kx) * NC_ + c, isbf);
    if (isbf) ((bf*)out)[t] = __float2bfloat16(acc);
    else      ((float*)out)[t] = acc;
}

// ---------------------------------------------------------------------------
extern "C" void kernel_launch(void* const* d_in, const int* in_sizes, int n_in,
                              void* d_out, int out_size, void* d_ws, size_t ws_size,
                              hipStream_t stream) {
    (void)in_sizes; (void)n_in; (void)out_size;
    const int* ids   = (const int*)d_in[0];
    const int* amask = (const int*)d_in[1];
    const void* we  = d_in[2];
    const void* pe  = d_in[3];
    const void* te  = d_in[4];
    const void* lng = d_in[5];
    const void* lnb = d_in[6];
    const void* Wq  = d_in[7];
    const void* bq  = d_in[8];
    const void* Wk  = d_in[9];
    const void* bk  = d_in[10];
    const void* Wv  = d_in[11];
    const void* bv  = d_in[12];
    const void* Wo  = d_in[13];
    const void* bo  = d_in[14];
    const void* l1g = d_in[15];
    const void* l1b = d_in[16];
    const void* W1  = d_in[17];
    const void* b1  = d_in[18];
    const void* W2  = d_in[19];
    const void* b2  = d_in[20];
    const void* l2g = d_in[21];
    const void* l2b = d_in[22];
    const void* pW  = d_in[23];
    const void* pb  = d_in[24];
    const void* cW  = d_in[25];
    const void* cb  = d_in[26];

    // ---- workspace carve (runtime CB selection from ws_size) ----
    char* cur = (char*)d_ws;
    auto alloc = [&](size_t bytes) -> char* {
        char* p = cur;
        cur += (bytes + 255) & ~(size_t)255;
        return p;
    };
    float* x    = (float*)alloc(BSH_ * 4);
    float* r0   = (float*)alloc(BSH_ * 4);   // ctx split planes; FFN hidden hi spans r0+r1f
    float* r1f  = (float*)alloc(BSH_ * 4);   // q planes; Wo output fp32
    float* r2f  = (float*)alloc(BSH_ * 4);   // k planes; FFN hidden lo spans r2f+r3f
    float* r3f  = (float*)alloc(BSH_ * 4);   // v planes
    float* z    = (float*)alloc(BSH_ * 4);   // W2 output fp32
    float* tab  = (float*)alloc(129 * 64 * 4);
    float* mb   = (float*)alloc(BS_ * 4);
    float* pool = (float*)alloc(B_ * H_ * 4);
    float* sa   = (float*)alloc(B_ * H_ * 4);
    bf* tabTh   = (bf*)alloc(64 * TAUG_ * 2);
    bf* tabTl   = (bf*)alloc(64 * TAUG_ * 2);
    bf* tabSh   = (bf*)alloc(TPAD_ * 64 * 2);
    bf* tabSl   = (bf*)alloc(TPAD_ * 64 * 2);
    int* flag   = (int*)alloc(256);

    const size_t fixed = (size_t)(cur - (char*)d_ws);
    auto regA_sz = [&](int CB) {  // wth/wtl  U  qrel
        size_t wt = (size_t)2 * H_ * FF_ * 2;
        size_t qr = (size_t)CB * NH_ * S_ * TPAD_ * 4;
        return (wt > qr ? wt : qr);
    };
    auto regB_sz = [&](int CB) {  // xh/xl  U  scores
        size_t xs = (size_t)4 * BSH_;
        size_t sc = (size_t)CB * NH_ * S_ * S_ * 4;
        return (xs > sc ? xs : sc);
    };
    auto need = [&](int CB) {
        return fixed + regA_sz(CB) + regB_sz(CB)
             + (size_t)CB * NH_ * S_ * KAUG_ * 2 * 2      // pah+pal
             + (size_t)CB * NH_ * 64 * KAUG_ * 2 * 2      // vah+val
             + 4096;
    };
    int CB = 8;
    while (CB > 1 && need(CB) > ws_size) CB >>= 1;

    char* regA = alloc(regA_sz(CB));
    char* regB = alloc(regB_sz(CB));
    bf* pah  = (bf*)alloc((size_t)CB * NH_ * S_ * KAUG_ * 2 * 2);
    bf* pal  = pah + (size_t)CB * NH_ * S_ * KAUG_;
    bf* vah  = (bf*)alloc((size_t)CB * NH_ * 64 * KAUG_ * 2 * 2);
    bf* val_ = vah + (size_t)CB * NH_ * 64 * KAUG_;

    bf*    wth   = (bf*)regA;
    bf*    wtl   = wth + (size_t)H_ * FF_;
    float* qrelb = (float*)regA;
    bf*    xh    = (bf*)regB;
    bf*    xl    = xh + BSH_;
    float* scb   = (float*)regB;

    bf* qh  = (bf*)r1f; bf* qlp = qh  + BSH_;
    bf* khp = (bf*)r2f; bf* klp = khp + BSH_;
    bf* vhp = (bf*)r3f; bf* vlp = vhp + BSH_;
    bf* ch  = (bf*)r0;  bf* cl  = ch  + BSH_;
    bf* hbh = (bf*)r0;                     // [4096,3072] spans r0+r1f
    bf* hbl = (bf*)r2f;                    // spans r2f+r3f

    detect_kernel<<<1, 64, 0, stream>>>((const unsigned int*)lng, flag);
    build_table_kernel<<<(129 * 64 + 255) / 256, 256, 0, stream>>>(tab);
    build_tabT_kernel<<<(64 * TAUG_ + 255) / 256, 256, 0, stream>>>(tab, tabTh, tabTl);
    build_tabS_kernel<<<(TPAD_ * 64 + 255) / 256, 256, 0, stream>>>(tab, tabSh, tabSl);
    maskbias_kernel<<<(BS_ + 255) / 256, 256, 0, stream>>>(amask, mb);
    embed_kernel<<<BS_, 256, 0, stream>>>(ids, we, pe, te, r0, flag);
    ln_kernel<<<BS_, 256, 0, stream>>>(x, xh, xl, r0, nullptr, lng, lnb, 0, flag);

    dim3 tpHH(H_ / 32, H_ / 32);
    dim3 tpHF(H_ / 32, FF_ / 32);
    dim3 tpFH(FF_ / 32, H_ / 32);
    dim3 gH(H_ / 128, BS_ / 128);
    dim3 gF(FF_ / 128, BS_ / 128);
    dim3 gQR(CB * S_ / 128, NH_, 3);
    dim3 gVA(NH_, 2, CB);
    dim3 gQK(4, 4, NH_ * CB);
    dim3 gSM(S_ / 4, NH_, CB);
    dim3 gPV(NH_, 4, CB);

    for (int l = 0; l < L_; ++l) {
        const size_t oHH = (size_t)l * H_ * H_;
        const size_t oH  = (size_t)l * H_;
        const size_t oHF = (size_t)l * H_ * FF_;
        const size_t oF  = (size_t)l * FF_;

        // ---- Q, K, V (split-bf16 outputs) ----
        transpose_split_kernel<<<tpHH, 256, 0, stream>>>(Wq, oHH, wth, wtl, H_, H_, flag);
        mgemm_kernel<<<gH, 256, 0, stream>>>(xh, xl, wth, wtl, bq, oH,
                                             nullptr, qh, qlp, BS_, H_, H_, 0, 1, flag);
        transpose_split_kernel<<<tpHH, 256, 0, stream>>>(Wk, oHH, wth, wtl, H_, H_, flag);
        mgemm_kernel<<<gH, 256, 0, stream>>>(xh, xl, wth, wtl, bk, oH,
                                             nullptr, khp, klp, BS_, H_, H_, 0, 1, flag);
        transpose_split_kernel<<<tpHH, 256, 0, stream>>>(Wv, oHH, wth, wtl, H_, H_, flag);
        mgemm_kernel<<<gH, 256, 0, stream>>>(xh, xl, wth, wtl, bv, oH,
                                             nullptr, vhp, vlp, BS_, H_, H_, 0, 1, flag);

        // ---- attention, chunked by CB batches ----
        for (int b0 = 0; b0 < B_; b0 += CB) {
            qrel_kernel<<<gQR, 256, 0, stream>>>(qh, qlp, tabSh, tabSl, qrelb, b0);
            vaug_kernel<<<gVA, 256, 0, stream>>>(vhp, vlp, tabTh, tabTl, vah, val_, b0);
            qk_kernel<<<gQK, 256, 0, stream>>>(qh, qlp, khp, klp, scb, b0);
            smrel_kernel<<<gSM, 256, 0, stream>>>(scb, qrelb, mb, pah, pal, b0);
            pv_kernel<<<gPV, 256, 0, stream>>>(pah, pal, vah, val_, ch, cl, b0);
        }

        // ---- output projection + LN1 ----
        transpose_split_kernel<<<tpHH, 256, 0, stream>>>(Wo, oHH, wth, wtl, H_, H_, flag);
        mgemm_kernel<<<gH, 256, 0, stream>>>(ch, cl, wth, wtl, bo, oH,
                                             r1f, nullptr, nullptr, BS_, H_, H_, 0, 0, flag);
        ln_kernel<<<BS_, 256, 0, stream>>>(x, xh, xl, r1f, x, l1g, l1b, oH, flag);

        // ---- FFN ----
        transpose_split_kernel<<<tpHF, 256, 0, stream>>>(W1, oHF, wth, wtl, H_, FF_, flag);
        mgemm_kernel<<<gF, 256, 0, stream>>>(xh, xl, wth, wtl, b1, oF,
                                             nullptr, hbh, hbl, BS_, FF_, H_, 1, 1, flag);
        transpose_split_kernel<<<tpFH, 256, 0, stream>>>(W2, oHF, wth, wtl, FF_, H_, flag);
        mgemm_kernel<<<gH, 256, 0, stream>>>(hbh, hbl, wth, wtl, b2, oH,
                                             z, nullptr, nullptr, BS_, H_, FF_, 0, 0, flag);
        ln_kernel<<<BS_, 256, 0, stream>>>(x, xh, xl, z, x, l2g, l2b, oH, flag);
    }

    pool_kernel<<<B_, 256, 0, stream>>>(x, pW, pb, pool, flag);
    seqavg_kernel<<<B_, 256, 0, stream>>>(x, sa);
    head_kernel<<<1, 64, 0, stream>>>(sa, pool, cW, cb, d_out, flag);
}

// Round 4
// 6869.067 us; speedup vs baseline: 6.8438x; 1.1376x over previous
//
#include <hip/hip_runtime.h>
#include <hip/hip_bf16.h>
#include <math.h>

typedef __hip_bfloat16 bf;

#define B_ 8
#define S_ 512
#define H_ 768
#define L_ 12
#define NH_ 12
#define HD_ 64
#define FF_ 3072
#define NC_ 6
#define BS_ (B_ * S_)          // 4096 tokens
#define BSH_ ((size_t)BS_ * H_)
#define KAUG_ 672              // 512 (P) + 129 (arel) + 31 pad, %32==0
#define TAUG_ 160              // padded rel-bucket count for vaug columns
#define TPAD_ 144              // padded rel-bucket count for qrel rows
#define QSTR_ 2304             // fused QKV row stride (3*H per token? no: 3*768)

typedef __attribute__((ext_vector_type(8))) short s16x8;   // 8 bf16 (4 VGPRs)
typedef __attribute__((ext_vector_type(4))) float fx4;     // MFMA accumulator

// Runtime-dtype load: isbf chosen by detect_kernel from ln_emb_g's bit pattern.
__device__ __forceinline__ float LD(const void* p, size_t i, int isbf) {
    return isbf ? __bfloat162float(((const bf*)p)[i]) : ((const float*)p)[i];
}

// async global->LDS, 16B per lane. LDS dest must be wave-uniform base (+lane*16).
__device__ __forceinline__ void gload16(const void* g, void* l) {
    __builtin_amdgcn_global_load_lds(
        (const __attribute__((address_space(1))) void*)g,
        (__attribute__((address_space(3))) void*)l, 16, 0, 0);
}

// Swizzled fragment reads (both-sides XOR, rule 21): row-major LDS tiles whose
// 16B chunks were permuted at stage time by chunk ^= (row & mask).
__device__ __forceinline__ s16x8 ldfrag64(const unsigned short* base, int row, int chunk) {
    return *(const s16x8*)((const char*)base + row * 128 + ((chunk ^ (row & 7)) << 4));
}
__device__ __forceinline__ s16x8 ldfrag32(const unsigned short* base, int row, int chunk) {
    return *(const s16x8*)((const char*)base + row * 64 + ((chunk ^ (row & 3)) << 4));
}

__device__ __forceinline__ float wred_sum(float v) {
#pragma unroll
    for (int o = 32; o; o >>= 1) v += __shfl_xor(v, o, 64);
    return v;
}
__device__ __forceinline__ float wred_max(float v) {
#pragma unroll
    for (int o = 32; o; o >>= 1) v = fmaxf(v, __shfl_xor(v, o, 64));
    return v;
}

// ---------------------------------------------------------------------------
__global__ void detect_kernel(const unsigned int* __restrict__ g, int* __restrict__ flag) {
    if (threadIdx.x == 0 && blockIdx.x == 0) {
        flag[0] = (g[0] == 0x3F800000u) ? 0 : 1;
        flag[1] = 0;   // constant fp32 flag (for fp32 concat'd bias)
    }
}

// ---------------------------------------------------------------------------
// Relative-position sinusoid table: [129, 64]. Match numpy: fp64 math -> fp32.
__global__ void build_table_kernel(float* __restrict__ tab) {
    int idx = blockIdx.x * 256 + threadIdx.x;
    if (idx >= 129 * 64) return;
    int p = idx >> 6, d = idx & 63;
    double angle = (double)p / pow(10000.0, (double)(2 * (d / 2)) / 64.0);
    tab[idx] = (float)((d & 1) ? cos(angle) : sin(angle));
}

// Transposed + split tab for the augmented-V build: tabT[d][t], t<129 real, rest 0.
__global__ void build_tabT_kernel(const float* __restrict__ tab,
                                  bf* __restrict__ th, bf* __restrict__ tl) {
    int idx = blockIdx.x * 256 + threadIdx.x;
    if (idx >= 64 * TAUG_) return;
    int d = idx / TAUG_, t = idx % TAUG_;
    float v = (t < 129) ? tab[t * 64 + d] : 0.0f;
    bf h = __float2bfloat16(v);
    th[idx] = h;
    tl[idx] = __float2bfloat16(v - __bfloat162float(h));
}

// t-major split tab [144][64] for the qrel MFMA B-operand.
__global__ void build_tabS_kernel(const float* __restrict__ tab,
                                  bf* __restrict__ th, bf* __restrict__ tl) {
    int idx = blockIdx.x * 256 + threadIdx.x;
    if (idx >= TPAD_ * 64) return;
    int t = idx >> 6;
    float v = (t < 129) ? tab[idx] : 0.0f;
    bf h = __float2bfloat16(v);
    th[idx] = h;
    tl[idx] = __float2bfloat16(v - __bfloat162float(h));
}

// ---------------------------------------------------------------------------
// Embedding sum (word + pos + type[0]) -> fp32
__global__ __launch_bounds__(256) void embed_kernel(
    const int* __restrict__ ids, const void* __restrict__ we,
    const void* __restrict__ pe, const void* __restrict__ te,
    float* __restrict__ y, const int* __restrict__ fl) {
    int isbf = *fl;
    int t = blockIdx.x;
    int s = t & (S_ - 1);
    int id = ids[t];
    size_t base = (size_t)t * H_;
    for (int c = threadIdx.x; c < H_; c += 256) {
        y[base + c] = LD(we, (size_t)id * H_ + c, isbf) +
                      LD(pe, (size_t)s * H_ + c, isbf) +
                      LD(te, c, isbf);
    }
}

// ---------------------------------------------------------------------------
__global__ void maskbias_kernel(const int* __restrict__ mask, float* __restrict__ mb) {
    int t = blockIdx.x * 256 + threadIdx.x;
    if (t < BS_) mb[t] = (1.0f - (float)mask[t]) * -10000.0f;
}

// ---------------------------------------------------------------------------
// Bias concat for fused QKV: out[0..2303] fp32 = [bq|bk|bv][off..off+767].
__global__ void biascat_kernel(const void* __restrict__ bq, const void* __restrict__ bk,
                               const void* __restrict__ bv, size_t off,
                               float* __restrict__ out, const int* __restrict__ fl) {
    int isbf = *fl;
    int t = blockIdx.x * 256 + threadIdx.x;
    if (t >= 3 * H_) return;
    const void* src = t < H_ ? bq : (t < 2 * H_ ? bk : bv);
    out[t] = LD(src, off + (t % H_), isbf);
}

// ---------------------------------------------------------------------------
// Barrier-free LayerNorm: 4 waves/block, one row per wave, shuffle reductions.
// out = LN(a (+ resid)) * g + b; optional split-bf16 planes. grid = BS_/4.
__global__ __launch_bounds__(256) void ln_kernel(
    float* out, bf* ohi, bf* olo, const float* a, const float* resid,
    const void* __restrict__ g, const void* __restrict__ b, size_t goff,
    const int* __restrict__ fl) {
    const int isbf = *fl;
    const int lane = threadIdx.x & 63, wv = threadIdx.x >> 6;
    const int row = blockIdx.x * 4 + wv;
    const size_t base = (size_t)row * H_;
    float v[12];
#pragma unroll
    for (int e = 0; e < 12; ++e) {
        const int c = lane + e * 64;
        v[e] = a[base + c];
        if (resid) v[e] += resid[base + c];
    }
    float s = 0.0f;
#pragma unroll
    for (int e = 0; e < 12; ++e) s += v[e];
    const float mu = wred_sum(s) * (1.0f / (float)H_);
    float q = 0.0f;
#pragma unroll
    for (int e = 0; e < 12; ++e) { v[e] -= mu; q += v[e] * v[e]; }
    const float rs = 1.0f / sqrtf(wred_sum(q) * (1.0f / (float)H_) + 1e-12f);
#pragma unroll
    for (int e = 0; e < 12; ++e) {
        const int c = lane + e * 64;
        float o = v[e] * rs * LD(g, goff + c, isbf) + LD(b, goff + c, isbf);
        out[base + c] = o;
        if (ohi) {
            bf h = __float2bfloat16(o);
            ohi[base + c] = h;
            olo[base + c] = __float2bfloat16(o - __bfloat162float(h));
        }
    }
}

// ---------------------------------------------------------------------------
// Transpose + split weights: W[K,N] (runtime dtype, woff elems) -> th,tl bf16 [N,K].
__global__ __launch_bounds__(256) void transpose_split_kernel(
    const void* __restrict__ W, size_t woff, bf* __restrict__ th, bf* __restrict__ tl,
    int K, int N, const int* __restrict__ fl) {
    __shared__ float s[32][33];
    const int isbf = *fl;
    const int tx = threadIdx.x & 31, ty = threadIdx.x >> 5;
    const int k0 = blockIdx.x * 32, n0 = blockIdx.y * 32;
#pragma unroll
    for (int i = 0; i < 4; ++i) {
        int k = k0 + ty + i * 8;
        s[ty + i * 8][tx] = LD(W, woff + (size_t)k * N + (n0 + tx), isbf);
    }
    __syncthreads();
#pragma unroll
    for (int i = 0; i < 4; ++i) {
        int n = n0 + ty + i * 8;
        float v = s[tx][ty + i * 8];
        bf h = __float2bfloat16(v);
        bf l = __float2bfloat16(v - __bfloat162float(h));
        th[(size_t)n * K + k0 + tx] = h;
        tl[(size_t)n * K + k0 + tx] = l;
    }
}

// ---------------------------------------------------------------------------
// Split-bf16 MFMA GEMM (3 products): C[M,N] = (Ah+Al)[M,K] @ (Bh+Bl)^T, B planes [N,K].
// Tile (MR*32) x 128, BK=32, 4 waves in 2x2; MR=4 -> 128 rows, MR=2 -> 64 rows.
template<int MR>
__global__ __launch_bounds__(256, 2) void mgemm_kernel(
    const bf* __restrict__ Ah, const bf* __restrict__ Al,
    const bf* __restrict__ Bh, const bf* __restrict__ Bl,
    const void* __restrict__ bias, size_t boff,
    float* __restrict__ C, bf* __restrict__ Chi, bf* __restrict__ Clo,
    int N, int K, int act, int split_out, const int* __restrict__ fl) {
    __shared__ __align__(16) unsigned short Ahs[MR * 32][32];
    __shared__ __align__(16) unsigned short Als[MR * 32][32];
    __shared__ __align__(16) unsigned short Bhs[128][32];
    __shared__ __align__(16) unsigned short Bls[128][32];
    const int tid  = threadIdx.x;
    const int lane = tid & 63;
    const int wid  = tid >> 6;
    const int wr   = wid >> 1, wc = wid & 1;
    const int m0 = blockIdx.y * (MR * 32), n0 = blockIdx.x * 128;
    const int srow = lane >> 2;
    const int scol = (lane & 3) * 8;

    const fx4 fzero = {0.f, 0.f, 0.f, 0.f};
    fx4 acc[MR][4];
#pragma unroll
    for (int i = 0; i < MR; ++i)
#pragma unroll
        for (int j = 0; j < 4; ++j) acc[i][j] = fzero;

    for (int k0 = 0; k0 < K; k0 += 32) {
#pragma unroll
        for (int t = 0; t < MR / 2; ++t) {
            const int r = wid * (MR * 8) + t * 16;
            const size_t ga = (size_t)(m0 + r + srow) * K + (k0 + scol);
            gload16(Ah + ga, &Ahs[r][0]);
            gload16(Al + ga, &Als[r][0]);
        }
#pragma unroll
        for (int t = 0; t < 2; ++t) {
            const int r = wid * 32 + t * 16;
            const size_t gb = (size_t)(n0 + r + srow) * K + (k0 + scol);
            gload16(Bh + gb, &Bhs[r][0]);
            gload16(Bl + gb, &Bls[r][0]);
        }
        __syncthreads();

        const int fr = lane & 15;
        const int ko = (lane >> 4) * 8;
        s16x8 ah[MR], al[MR], bh[4], bl[4];
#pragma unroll
        for (int f = 0; f < MR; ++f) {
            ah[f] = *(const s16x8*)&Ahs[wr * (MR * 16) + f * 16 + fr][ko];
            al[f] = *(const s16x8*)&Als[wr * (MR * 16) + f * 16 + fr][ko];
        }
#pragma unroll
        for (int f = 0; f < 4; ++f) {
            bh[f] = *(const s16x8*)&Bhs[wc * 64 + f * 16 + fr][ko];
            bl[f] = *(const s16x8*)&Bls[wc * 64 + f * 16 + fr][ko];
        }
#pragma unroll
        for (int im = 0; im < MR; ++im)
#pragma unroll
            for (int in = 0; in < 4; ++in) {
                acc[im][in] = __builtin_amdgcn_mfma_f32_16x16x32_bf16(ah[im], bh[in], acc[im][in], 0, 0, 0);
                acc[im][in] = __builtin_amdgcn_mfma_f32_16x16x32_bf16(ah[im], bl[in], acc[im][in], 0, 0, 0);
                acc[im][in] = __builtin_amdgcn_mfma_f32_16x16x32_bf16(al[im], bh[in], acc[im][in], 0, 0, 0);
            }
        __syncthreads();
    }

    const int isbf = *fl;
    const int cr0 = m0 + wr * (MR * 16) + (lane >> 4) * 4;
    const int cc0 = n0 + wc * 64 + (lane & 15);
#pragma unroll
    for (int in = 0; in < 4; ++in) {
        const int col = cc0 + in * 16;
        const float bv = LD(bias, boff + col, isbf);
#pragma unroll
        for (int im = 0; im < MR; ++im) {
#pragma unroll
            for (int r = 0; r < 4; ++r) {
                const int row = cr0 + im * 16 + r;
                float v = acc[im][in][r] + bv;
                if (act) v = 0.5f * v * (1.0f + erff(v * 0.70710678118654752f));
                if (split_out) {
                    bf h = __float2bfloat16(v);
                    bf l = __float2bfloat16(v - __bfloat162float(h));
                    Chi[(size_t)row * N + col] = h;
                    Clo[(size_t)row * N + col] = l;
                } else {
                    C[(size_t)row * N + col] = v;
                }
            }
        }
    }
}

// ---------------------------------------------------------------------------
// qrel[bb,h,i,t] = q[b,i,h,:] . tab[t,:]  (3-product split-bf16 MFMA).
// grid (CB*S/128, NH, 3), 256 thr. tabS planes are [144][64] t-major.
// q planes have row stride astr (fused QKV layout).
__global__ __launch_bounds__(256) void qrel_kernel(
    const bf* __restrict__ qh, const bf* __restrict__ ql,
    const bf* __restrict__ tabSh, const bf* __restrict__ tabSl,
    float* __restrict__ qrel, int astr, int b0) {
    const int tid = threadIdx.x, lane = tid & 63, wv = tid >> 6;
    const int rbase = blockIdx.x * 128;
    const int h = blockIdx.y;
    const int t0 = blockIdx.z * 48;
    const int fr = lane & 15, ko = (lane >> 4) * 8;
    const fx4 fz = {0.f, 0.f, 0.f, 0.f};
    fx4 acc[2][3];
#pragma unroll
    for (int m = 0; m < 2; ++m)
#pragma unroll
        for (int n = 0; n < 3; ++n) acc[m][n] = fz;
#pragma unroll
    for (int ks = 0; ks < 2; ++ks) {
        s16x8 a_h[2], a_l[2], b_h[3], b_l[3];
#pragma unroll
        for (int m = 0; m < 2; ++m) {
            const int row = rbase + wv * 32 + m * 16 + fr;
            const size_t ga = ((size_t)(b0 * S_) + row) * astr + h * 64 + ks * 32 + ko;
            a_h[m] = *(const s16x8*)(qh + ga);
            a_l[m] = *(const s16x8*)(ql + ga);
        }
#pragma unroll
        for (int n = 0; n < 3; ++n) {
            const int trow = t0 + n * 16 + fr;
            const size_t gb = (size_t)trow * 64 + ks * 32 + ko;
            b_h[n] = *(const s16x8*)(tabSh + gb);
            b_l[n] = *(const s16x8*)(tabSl + gb);
        }
#pragma unroll
        for (int m = 0; m < 2; ++m)
#pragma unroll
            for (int n = 0; n < 3; ++n) {
                acc[m][n] = __builtin_amdgcn_mfma_f32_16x16x32_bf16(a_h[m], b_h[n], acc[m][n], 0, 0, 0);
                acc[m][n] = __builtin_amdgcn_mfma_f32_16x16x32_bf16(a_h[m], b_l[n], acc[m][n], 0, 0, 0);
                acc[m][n] = __builtin_amdgcn_mfma_f32_16x16x32_bf16(a_l[m], b_h[n], acc[m][n], 0, 0, 0);
            }
    }
    const int rr = (lane >> 4) * 4, cc = lane & 15;
#pragma unroll
    for (int m = 0; m < 2; ++m)
#pragma unroll
        for (int n = 0; n < 3; ++n)
#pragma unroll
            for (int r = 0; r < 4; ++r) {
                const int row = rbase + wv * 32 + m * 16 + rr + r;
                const int t = t0 + n * 16 + cc;
                const int bb = row >> 9, ii = row & (S_ - 1);
                qrel[(((size_t)bb * NH_ + h) * S_ + ii) * TPAD_ + t] = acc[m][n][r];
            }
}

// ---------------------------------------------------------------------------
// QK^T: scores[bb,h,i,j] raw. grid (jt=4, it=4, NH*CB), 256 thr. q/k stride astr.
__global__ __launch_bounds__(256, 2) void qk_kernel(
    const bf* __restrict__ qh, const bf* __restrict__ ql,
    const bf* __restrict__ kh, const bf* __restrict__ kl,
    float* __restrict__ sc, int astr, int b0) {
    __shared__ __align__(16) unsigned short Qh[128][64];
    __shared__ __align__(16) unsigned short Ql_[128][64];
    __shared__ __align__(16) unsigned short Kh[128][64];
    __shared__ __align__(16) unsigned short Kl[128][64];
    const int tid = threadIdx.x, lane = tid & 63, wv = tid >> 6;
    const int j0 = blockIdx.x * 128, i0 = blockIdx.y * 128;
    const int h = blockIdx.z % NH_, bb = blockIdx.z / NH_;
    const int b = b0 + bb;
    const int srow = lane >> 3;
    const int schunk = (lane & 7) ^ (srow & 7);
#pragma unroll
    for (int t = 0; t < 4; ++t) {
        const int r = wv * 32 + t * 8;
        const size_t ga = (size_t)(b * S_ + i0 + r + srow) * astr + h * 64 + schunk * 8;
        const size_t gb = (size_t)(b * S_ + j0 + r + srow) * astr + h * 64 + schunk * 8;
        gload16(qh + ga, &Qh[r][0]);
        gload16(ql + ga, &Ql_[r][0]);
        gload16(kh + gb, &Kh[r][0]);
        gload16(kl + gb, &Kl[r][0]);
    }
    __syncthreads();
    const int fr = lane & 15, g = lane >> 4;
    const int wr = wv >> 1, wc = wv & 1;
    const fx4 fz = {0.f, 0.f, 0.f, 0.f};
    fx4 acc[4][4];
#pragma unroll
    for (int i = 0; i < 4; ++i)
#pragma unroll
        for (int j = 0; j < 4; ++j) acc[i][j] = fz;
#pragma unroll
    for (int ks = 0; ks < 2; ++ks) {
        s16x8 ah[4], al[4], bh[4], bl[4];
#pragma unroll
        for (int m = 0; m < 4; ++m) {
            const int row = wr * 64 + m * 16 + fr;
            ah[m] = ldfrag64(&Qh[0][0], row, ks * 4 + g);
            al[m] = ldfrag64(&Ql_[0][0], row, ks * 4 + g);
        }
#pragma unroll
        for (int n = 0; n < 4; ++n) {
            const int row = wc * 64 + n * 16 + fr;
            bh[n] = ldfrag64(&Kh[0][0], row, ks * 4 + g);
            bl[n] = ldfrag64(&Kl[0][0], row, ks * 4 + g);
        }
#pragma unroll
        for (int m = 0; m < 4; ++m)
#pragma unroll
            for (int n = 0; n < 4; ++n) {
                acc[m][n] = __builtin_amdgcn_mfma_f32_16x16x32_bf16(ah[m], bh[n], acc[m][n], 0, 0, 0);
                acc[m][n] = __builtin_amdgcn_mfma_f32_16x16x32_bf16(ah[m], bl[n], acc[m][n], 0, 0, 0);
                acc[m][n] = __builtin_amdgcn_mfma_f32_16x16x32_bf16(al[m], bh[n], acc[m][n], 0, 0, 0);
            }
    }
    const int rr = (lane >> 4) * 4, cc = lane & 15;
#pragma unroll
    for (int m = 0; m < 4; ++m)
#pragma unroll
        for (int n = 0; n < 4; ++n)
#pragma unroll
            for (int r = 0; r < 4; ++r) {
                const int ii = i0 + wr * 64 + m * 16 + rr + r;
                const int jj = j0 + wc * 64 + n * 16 + cc;
                sc[(((size_t)bb * NH_ + h) * S_ + ii) * S_ + jj] = acc[m][n][r];
            }
}

// ---------------------------------------------------------------------------
// Wave-per-row softmax + augmented-P emit. grid (S/4, NH, CB), 256 thr (4 waves).
__global__ __launch_bounds__(256) void smrel_kernel(
    const float* __restrict__ scores, const float* __restrict__ qrel,
    const float* __restrict__ mb,
    bf* __restrict__ pah, bf* __restrict__ pal, int b0) {
    const int lane = threadIdx.x & 63;
    const int wv = threadIdx.x >> 6;
    const int i = blockIdx.x * 4 + wv;
    const int h = blockIdx.y, bb = blockIdx.z;
    const int b = b0 + bb;
    const size_t srow = ((size_t)bb * NH_ + h) * S_ + i;
    const size_t qbase = srow * TPAD_;

    float s[8];
    float lmax = -1e30f;
#pragma unroll
    for (int rep = 0; rep < 8; ++rep) {
        const int j = lane + rep * 64;
        int t = j - i; t = t < -64 ? -64 : (t > 64 ? 64 : t);
        float v = (scores[srow * S_ + j] + qrel[qbase + t + 64]) * 0.125f + mb[b * S_ + j];
        s[rep] = v;
        lmax = fmaxf(lmax, v);
    }
    const float mx = wred_max(lmax);
    float lsum = 0.0f;
#pragma unroll
    for (int rep = 0; rep < 8; ++rep) {
        s[rep] = expf(s[rep] - mx);
        lsum += s[rep];
    }
    const float inv = 1.0f / wred_sum(lsum);

    const size_t rowbase = srow * KAUG_;
#pragma unroll
    for (int e = 0; e < 3; ++e) {
        const int t = lane + e * 64;
        if (t < TAUG_) {
            pah[rowbase + 512 + t] = __float2bfloat16(0.0f);
            pal[rowbase + 512 + t] = __float2bfloat16(0.0f);
        }
    }
    float s_lo = 0.0f, s_hi = 0.0f;
#pragma unroll
    for (int rep = 0; rep < 8; ++rep) {
        const int j = lane + rep * 64;
        const float v = s[rep] * inv;
        bf hh = __float2bfloat16(v);
        pah[rowbase + j] = hh;
        pal[rowbase + j] = __float2bfloat16(v - __bfloat162float(hh));
        const int d = j - i;
        if (d <= -64) s_lo += s[rep];
        else if (d >= 64) s_hi += s[rep];
        else {
            pah[rowbase + 512 + d + 64] = hh;
            pal[rowbase + 512 + d + 64] = __float2bfloat16(v - __bfloat162float(hh));
        }
    }
    s_lo = wred_sum(s_lo);
    s_hi = wred_sum(s_hi);
    if (lane == 0) {
        float v0 = s_lo * inv;
        bf h0 = __float2bfloat16(v0);
        pah[rowbase + 512] = h0;
        pal[rowbase + 512] = __float2bfloat16(v0 - __bfloat162float(h0));
        float v1 = s_hi * inv;
        bf h1 = __float2bfloat16(v1);
        pah[rowbase + 512 + 128] = h1;
        pal[rowbase + 512 + 128] = __float2bfloat16(v1 - __bfloat162float(h1));
    }
}

// ---------------------------------------------------------------------------
// Build augmented V^T: vaug[bb][h][d][0..511]=V^T, [512..671]=tabT pad.
// grid (NH, 2, CB), 256 thr. v planes have row stride astr.
__global__ __launch_bounds__(256) void vaug_kernel(
    const bf* __restrict__ vh, const bf* __restrict__ vl,
    const bf* __restrict__ tabTh, const bf* __restrict__ tabTl,
    bf* __restrict__ vah, bf* __restrict__ val_, int astr, int b0) {
    __shared__ unsigned short tile[64][71];
    const int h = blockIdx.x, pl = blockIdx.y, bb = blockIdx.z;
    const int b = b0 + bb;
    const bf* src  = pl ? vl : vh;
    bf*       dst  = pl ? val_ : vah;
    const bf* tsrc = pl ? tabTl : tabTh;
    const int tid = threadIdx.x;
    const size_t dbase = ((size_t)bb * NH_ + h) * 64;
    for (int j0 = 0; j0 < S_; j0 += 64) {
        for (int idx = tid; idx < 4096; idx += 256) {
            int jj = idx >> 6, d = idx & 63;
            tile[jj][d] = *(const unsigned short*)&src[(size_t)(b * S_ + j0 + jj) * astr + h * 64 + d];
        }
        __syncthreads();
        for (int idx = tid; idx < 4096; idx += 256) {
            int d = idx >> 6, jj = idx & 63;
            *(unsigned short*)&dst[(dbase + d) * KAUG_ + j0 + jj] = tile[jj][d];
        }
        __syncthreads();
    }
    for (int idx = tid; idx < 64 * TAUG_; idx += 256) {
        int d = idx / TAUG_, t = idx % TAUG_;
        *(unsigned short*)&dst[(dbase + d) * KAUG_ + 512 + t] =
            *(const unsigned short*)&tsrc[idx];
    }
}

// ---------------------------------------------------------------------------
// ctx = [P|arel] @ [V; tab]: grid (NH, 4, CB). M=128, N=64, K=672.
// Output: split-bf16 context planes [B,S,H] (feeds the Wo GEMM directly).
__global__ __launch_bounds__(256, 2) void pv_kernel(
    const bf* __restrict__ pah, const bf* __restrict__ pal,
    const bf* __restrict__ vah, const bf* __restrict__ val_,
    bf* __restrict__ ch, bf* __restrict__ cl, int b0) {
    __shared__ __align__(16) unsigned short Ah[128][32];
    __shared__ __align__(16) unsigned short Al[128][32];
    __shared__ __align__(16) unsigned short Bh[64][32];
    __shared__ __align__(16) unsigned short Bl[64][32];
    const int tid = threadIdx.x, lane = tid & 63, wv = tid >> 6;
    const int h = blockIdx.x, i0 = blockIdx.y * 128, bb = blockIdx.z;
    const int b = b0 + bb;
    const int srow = lane >> 2;
    const int schunk = (lane & 3) ^ (srow & 3);
    const fx4 fz = {0.f, 0.f, 0.f, 0.f};
    fx4 acc[2][4];
#pragma unroll
    for (int m = 0; m < 2; ++m)
#pragma unroll
        for (int n = 0; n < 4; ++n) acc[m][n] = fz;

    for (int k0 = 0; k0 < KAUG_; k0 += 32) {
#pragma unroll
        for (int t = 0; t < 2; ++t) {
            const int r = wv * 32 + t * 16;
            const size_t ga = (((size_t)bb * NH_ + h) * S_ + i0 + r + srow) * KAUG_ + k0 + schunk * 8;
            gload16(pah + ga, &Ah[r][0]);
            gload16(pal + ga, &Al[r][0]);
        }
        {
            const int r = wv * 16;
            const size_t gb = (((size_t)bb * NH_ + h) * 64 + r + srow) * KAUG_ + k0 + schunk * 8;
            gload16(vah + gb, &Bh[r][0]);
            gload16(val_ + gb, &Bl[r][0]);
        }
        __syncthreads();
        const int fr = lane & 15, g = lane >> 4;
        s16x8 a_h[2], a_l[2], b_h[4], b_l[4];
#pragma unroll
        for (int m = 0; m < 2; ++m) {
            const int row = wv * 32 + m * 16 + fr;
            a_h[m] = ldfrag32(&Ah[0][0], row, g);
            a_l[m] = ldfrag32(&Al[0][0], row, g);
        }
#pragma unroll
        for (int n = 0; n < 4; ++n) {
            const int row = n * 16 + fr;
            b_h[n] = ldfrag32(&Bh[0][0], row, g);
            b_l[n] = ldfrag32(&Bl[0][0], row, g);
        }
#pragma unroll
        for (int m = 0; m < 2; ++m)
#pragma unroll
            for (int n = 0; n < 4; ++n) {
                acc[m][n] = __builtin_amdgcn_mfma_f32_16x16x32_bf16(a_h[m], b_h[n], acc[m][n], 0, 0, 0);
                acc[m][n] = __builtin_amdgcn_mfma_f32_16x16x32_bf16(a_h[m], b_l[n], acc[m][n], 0, 0, 0);
                acc[m][n] = __builtin_amdgcn_mfma_f32_16x16x32_bf16(a_l[m], b_h[n], acc[m][n], 0, 0, 0);
            }
        __syncthreads();
    }
    const int rr = (lane >> 4) * 4, cc = lane & 15;
#pragma unroll
    for (int m = 0; m < 2; ++m)
#pragma unroll
        for (int n = 0; n < 4; ++n)
#pragma unroll
            for (int r = 0; r < 4; ++r) {
                const int row = i0 + wv * 32 + m * 16 + rr + r;
                const int d = n * 16 + cc;
                const float v = acc[m][n][r];
                bf hh = __float2bfloat16(v);
                const size_t o = (size_t)(b * S_ + row) * H_ + h * 64 + d;
                ch[o] = hh;
                cl[o] = __float2bfloat16(v - __bfloat162float(hh));
            }
}

// ---------------------------------------------------------------------------
__global__ __launch_bounds__(256) void pool_kernel(
    const float* __restrict__ x, const void* __restrict__ pW,
    const void* __restrict__ pb, float* __restrict__ pooled,
    const int* __restrict__ fl) {
    int isbf = *fl;
    int b = blockIdx.x;
    const float* xr = x + (size_t)b * S_ * H_;
    for (int n = threadIdx.x; n < H_; n += 256) {
        float acc = LD(pb, n, isbf);
        for (int kx = 0; kx < H_; ++kx)
            acc += xr[kx] * LD(pW, (size_t)kx * H_ + n, isbf);
        pooled[b * H_ + n] = tanhf(acc);
    }
}

__global__ __launch_bounds__(256) void seqavg_kernel(
    const float* __restrict__ x, float* __restrict__ sa) {
    int b = blockIdx.x;
    for (int c = threadIdx.x; c < H_; c += 256) {
        float s = 0.0f;
        for (int j = 0; j < S_; ++j) s += x[((size_t)b * S_ + j) * H_ + c];
        sa[b * H_ + c] = s * (1.0f / (float)S_);
    }
}

__global__ void head_kernel(const float* __restrict__ sa, const float* __restrict__ pooled,
                            const void* __restrict__ cW, const void* __restrict__ cb,
                            void* __restrict__ out, const int* __restrict__ fl) {
    int isbf = *fl;
    int t = threadIdx.x;
    if (t >= B_ * NC_) return;
    int b = t / NC_, c = t % NC_;
    float acc = LD(cb, c, isbf);
    for (int kx = 0; kx < H_; ++kx)
        acc += sa[b * H_ + kx] * LD(cW, (size_t)kx * NC_ + c, isbf);
    for (int kx = 0; kx < H_; ++kx)
        acc += pooled[b * H_ + kx] * LD(cW, (size_t)(H_ + kx) * NC_ + c, isbf);
    if (isbf) ((bf*)out)[t] = __float2bfloat16(acc);
    else      ((float*)out)[t] = acc;
}

// ---------------------------------------------------------------------------
extern "C" void kernel_launch(void* const* d_in, const int* in_sizes, int n_in,
                              void* d_out, int out_size, void* d_ws, size_t ws_size,
                              hipStream_t stream) {
    (void)in_sizes; (void)n_in; (void)out_size;
    const int* ids   = (const int*)d_in[0];
    const int* amask = (const int*)d_in[1];
    const void* we  = d_in[2];
    const void* pe  = d_in[3];
    const void* te  = d_in[4];
    const void* lng = d_in[5];
    const void* lnb = d_in[6];
    const void* Wq  = d_in[7];
    const void* bq  = d_in[8];
    const void* Wk  = d_in[9];
    const void* bk  = d_in[10];
    const void* Wv  = d_in[11];
    const void* bv  = d_in[12];
    const void* Wo  = d_in[13];
    const void* bo  = d_in[14];
    const void* l1g = d_in[15];
    const void* l1b = d_in[16];
    const void* W1  = d_in[17];
    const void* b1  = d_in[18];
    const void* W2  = d_in[19];
    const void* b2  = d_in[20];
    const void* l2g = d_in[21];
    const void* l2b = d_in[22];
    const void* pW  = d_in[23];
    const void* pb  = d_in[24];
    const void* cW  = d_in[25];
    const void* cb  = d_in[26];

    // ---- workspace carve (runtime CB selection from ws_size) ----
    char* cur = (char*)d_ws;
    auto alloc = [&](size_t bytes) -> char* {
        char* p = cur;
        cur += (bytes + 255) & ~(size_t)255;
        return p;
    };
    float* x    = (float*)alloc(BSH_ * 4);
    float* r0   = (float*)alloc(BSH_ * 4);   // ctx split planes; FFN hidden hi spans r0+r1f
    float* r1f  = (float*)alloc(BSH_ * 4);   // qkv planes span r1f..r3f
    float* r2f  = (float*)alloc(BSH_ * 4);   // FFN hidden lo spans r2f+r3f
    float* r3f  = (float*)alloc(BSH_ * 4);
    float* z    = (float*)alloc(BSH_ * 4);   // Wo / W2 fp32 outputs
    float* tab  = (float*)alloc(129 * 64 * 4);
    float* mb   = (float*)alloc(BS_ * 4);
    float* pool = (float*)alloc(B_ * H_ * 4);
    float* sa   = (float*)alloc(B_ * H_ * 4);
    float* bqkv = (float*)alloc(3 * H_ * 4);
    bf* tabTh   = (bf*)alloc(64 * TAUG_ * 2);
    bf* tabTl   = (bf*)alloc(64 * TAUG_ * 2);
    bf* tabSh   = (bf*)alloc(TPAD_ * 64 * 2);
    bf* tabSl   = (bf*)alloc(TPAD_ * 64 * 2);
    int* flag   = (int*)alloc(256);
    int* zflag  = flag + 1;

    const size_t fixed = (size_t)(cur - (char*)d_ws);
    auto regA_sz = [&](int CB) {  // wth/wtl  U  qrel
        size_t wt = (size_t)2 * H_ * FF_ * 2;
        size_t qr = (size_t)CB * NH_ * S_ * TPAD_ * 4;
        return (wt > qr ? wt : qr);
    };
    auto regB_sz = [&](int CB) {  // xh/xl  U  scores
        size_t xs = (size_t)4 * BSH_;
        size_t sc = (size_t)CB * NH_ * S_ * S_ * 4;
        return (xs > sc ? xs : sc);
    };
    auto need = [&](int CB) {
        return fixed + regA_sz(CB) + regB_sz(CB)
             + (size_t)CB * NH_ * S_ * KAUG_ * 2 * 2      // pah+pal
             + (size_t)CB * NH_ * 64 * KAUG_ * 2 * 2      // vah+val
             + 4096;
    };
    int CB = 8;
    while (CB > 1 && need(CB) > ws_size) CB >>= 1;

    char* regA = alloc(regA_sz(CB));
    char* regB = alloc(regB_sz(CB));
    bf* pah  = (bf*)alloc((size_t)CB * NH_ * S_ * KAUG_ * 2 * 2);
    bf* pal  = pah + (size_t)CB * NH_ * S_ * KAUG_;
    bf* vah  = (bf*)alloc((size_t)CB * NH_ * 64 * KAUG_ * 2 * 2);
    bf* val_ = vah + (size_t)CB * NH_ * 64 * KAUG_;

    bf*    wth   = (bf*)regA;                 // transposed weights (also stacked QKV)
    bf*    wtl   = wth + (size_t)H_ * FF_;
    float* qrelb = (float*)regA;
    bf*    xh    = (bf*)regB;
    bf*    xl    = xh + BSH_;
    float* scb   = (float*)regB;

    // fused QKV output planes: [4096][2304] hi + lo, aliasing r1f..r3f (37.7 MB)
    bf* qkvh = (bf*)r1f;
    bf* qkvl = qkvh + (size_t)BS_ * QSTR_;
    bf* ch   = (bf*)r0;  bf* cl = ch + BSH_;  // pv context planes
    bf* hbh  = (bf*)r0;                       // FFN hidden hi spans r0+r1f
    bf* hbl  = (bf*)r2f;                      // FFN hidden lo spans r2f+r3f

    detect_kernel<<<1, 64, 0, stream>>>((const unsigned int*)lng, flag);
    build_table_kernel<<<(129 * 64 + 255) / 256, 256, 0, stream>>>(tab);
    build_tabT_kernel<<<(64 * TAUG_ + 255) / 256, 256, 0, stream>>>(tab, tabTh, tabTl);
    build_tabS_kernel<<<(TPAD_ * 64 + 255) / 256, 256, 0, stream>>>(tab, tabSh, tabSl);
    maskbias_kernel<<<(BS_ + 255) / 256, 256, 0, stream>>>(amask, mb);
    embed_kernel<<<BS_, 256, 0, stream>>>(ids, we, pe, te, r0, flag);
    ln_kernel<<<BS_ / 4, 256, 0, stream>>>(x, xh, xl, r0, nullptr, lng, lnb, 0, flag);

    dim3 tpHH(H_ / 32, H_ / 32);
    dim3 tpHF(H_ / 32, FF_ / 32);
    dim3 tpFH(FF_ / 32, H_ / 32);
    dim3 gQKV(3 * H_ / 128, BS_ / 128);   // (18, 32) = 576 blocks
    dim3 gH64(H_ / 128, BS_ / 64);        // (6, 64)  = 384 blocks, MR=2
    dim3 gF(FF_ / 128, BS_ / 128);        // (24, 32) = 768 blocks
    dim3 gQR(CB * S_ / 128, NH_, 3);
    dim3 gVA(NH_, 2, CB);
    dim3 gQK(4, 4, NH_ * CB);
    dim3 gSM(S_ / 4, NH_, CB);
    dim3 gPV(NH_, 4, CB);

    for (int l = 0; l < L_; ++l) {
        const size_t oHH = (size_t)l * H_ * H_;
        const size_t oH  = (size_t)l * H_;
        const size_t oHF = (size_t)l * H_ * FF_;
        const size_t oF  = (size_t)l * FF_;

        // ---- fused QKV GEMM: N = 2304, stacked transposed weights ----
        transpose_split_kernel<<<tpHH, 256, 0, stream>>>(Wq, oHH, wth, wtl, H_, H_, flag);
        transpose_split_kernel<<<tpHH, 256, 0, stream>>>(Wk, oHH,
            wth + (size_t)H_ * H_, wtl + (size_t)H_ * H_, H_, H_, flag);
        transpose_split_kernel<<<tpHH, 256, 0, stream>>>(Wv, oHH,
            wth + (size_t)2 * H_ * H_, wtl + (size_t)2 * H_ * H_, H_, H_, flag);
        biascat_kernel<<<(3 * H_ + 255) / 256, 256, 0, stream>>>(bq, bk, bv, oH, bqkv, flag);
        mgemm_kernel<4><<<gQKV, 256, 0, stream>>>(xh, xl, wth, wtl, bqkv, 0,
            nullptr, qkvh, qkvl, QSTR_, H_, 0, 1, zflag);

        // ---- attention, chunked by CB batches ----
        for (int b0 = 0; b0 < B_; b0 += CB) {
            qrel_kernel<<<gQR, 256, 0, stream>>>(qkvh, qkvl, tabSh, tabSl, qrelb, QSTR_, b0);
            vaug_kernel<<<gVA, 256, 0, stream>>>(qkvh + 2 * H_, qkvl + 2 * H_,
                tabTh, tabTl, vah, val_, QSTR_, b0);
            qk_kernel<<<gQK, 256, 0, stream>>>(qkvh, qkvl, qkvh + H_, qkvl + H_,
                scb, QSTR_, b0);
            smrel_kernel<<<gSM, 256, 0, stream>>>(scb, qrelb, mb, pah, pal, b0);
            pv_kernel<<<gPV, 256, 0, stream>>>(pah, pal, vah, val_, ch, cl, b0);
        }

        // ---- output projection + LN1 ----
        transpose_split_kernel<<<tpHH, 256, 0, stream>>>(Wo, oHH, wth, wtl, H_, H_, flag);
        mgemm_kernel<2><<<gH64, 256, 0, stream>>>(ch, cl, wth, wtl, bo, oH,
            z, nullptr, nullptr, H_, H_, 0, 0, flag);
        ln_kernel<<<BS_ / 4, 256, 0, stream>>>(x, xh, xl, z, x, l1g, l1b, oH, flag);

        // ---- FFN ----
        transpose_split_kernel<<<tpHF, 256, 0, stream>>>(W1, oHF, wth, wtl, H_, FF_, flag);
        mgemm_kernel<4><<<gF, 256, 0, stream>>>(xh, xl, wth, wtl, b1, oF,
            nullptr, hbh, hbl, FF_, H_, 1, 1, flag);
        transpose_split_kernel<<<tpFH, 256, 0, stream>>>(W2, oHF, wth, wtl, FF_, H_, flag);
        mgemm_kernel<2><<<gH64, 256, 0, stream>>>(hbh, hbl, wth, wtl, b2, oH,
            z, nullptr, nullptr, H_, FF_, 0, 0, flag);
        ln_kernel<<<BS_ / 4, 256, 0, stream>>>(x, xh, xl, z, x, l2g, l2b, oH, flag);
    }

    pool_kernel<<<B_, 256, 0, stream>>>(x, pW, pb, pool, flag);
    seqavg_kernel<<<B_, 256, 0, stream>>>(x, sa);
    head_kernel<<<1, 64, 0, stream>>>(sa, pool, cW, cb, d_out, flag);
}

// Round 5
// 6690.414 us; speedup vs baseline: 7.0266x; 1.0267x over previous
//
#include <hip/hip_runtime.h>
#include <hip/hip_bf16.h>
#include <math.h>

typedef __hip_bfloat16 bf;

#define B_ 8
#define S_ 512
#define H_ 768
#define L_ 12
#define NH_ 12
#define HD_ 64
#define FF_ 3072
#define NC_ 6
#define BS_ (B_ * S_)          // 4096 tokens
#define BSH_ ((size_t)BS_ * H_)
#define KAUG_ 672              // 512 (P) + 129 (arel) + 31 pad, %32==0
#define TAUG_ 160              // padded rel-bucket count for vaug columns
#define TPAD_ 144              // padded rel-bucket count for qrel rows
#define QSTR_ 2304             // fused QKV row stride

typedef __attribute__((ext_vector_type(8))) short s16x8;   // 8 bf16 (4 VGPRs)
typedef __attribute__((ext_vector_type(4))) float fx4;     // MFMA accumulator

__device__ __forceinline__ float LD(const void* p, size_t i, int isbf) {
    return isbf ? __bfloat162float(((const bf*)p)[i]) : ((const float*)p)[i];
}

// async global->LDS, 16B per lane. LDS dest must be wave-uniform base (+lane*16).
__device__ __forceinline__ void gload16(const void* g, void* l) {
    __builtin_amdgcn_global_load_lds(
        (const __attribute__((address_space(1))) void*)g,
        (__attribute__((address_space(3))) void*)l, 16, 0, 0);
}

// Swizzled fragment reads (both-sides XOR, rule 21).
__device__ __forceinline__ s16x8 ldfrag64(const unsigned short* base, int row, int chunk) {
    return *(const s16x8*)((const char*)base + row * 128 + ((chunk ^ (row & 7)) << 4));
}
__device__ __forceinline__ s16x8 ldfrag32(const unsigned short* base, int row, int chunk) {
    return *(const s16x8*)((const char*)base + row * 64 + ((chunk ^ (row & 3)) << 4));
}

__device__ __forceinline__ float wred_sum(float v) {
#pragma unroll
    for (int o = 32; o; o >>= 1) v += __shfl_xor(v, o, 64);
    return v;
}

// 16-lane-group reductions (combine col-slices of a row held across lane&15)
__device__ __forceinline__ float gred_max(float v) {
#pragma unroll
    for (int o = 1; o < 16; o <<= 1) v = fmaxf(v, __shfl_xor(v, o, 64));
    return v;
}
__device__ __forceinline__ float gred_sum(float v) {
#pragma unroll
    for (int o = 1; o < 16; o <<= 1) v += __shfl_xor(v, o, 64);
    return v;
}

// ---------------------------------------------------------------------------
__global__ void detect_kernel(const unsigned int* __restrict__ g, int* __restrict__ flag) {
    if (threadIdx.x == 0 && blockIdx.x == 0) {
        flag[0] = (g[0] == 0x3F800000u) ? 0 : 1;
        flag[1] = 0;   // constant fp32 flag (for fp32 concat'd bias)
    }
}

// ---------------------------------------------------------------------------
__global__ void build_table_kernel(float* __restrict__ tab) {
    int idx = blockIdx.x * 256 + threadIdx.x;
    if (idx >= 129 * 64) return;
    int p = idx >> 6, d = idx & 63;
    double angle = (double)p / pow(10000.0, (double)(2 * (d / 2)) / 64.0);
    tab[idx] = (float)((d & 1) ? cos(angle) : sin(angle));
}

__global__ void build_tabT_kernel(const float* __restrict__ tab,
                                  bf* __restrict__ th, bf* __restrict__ tl) {
    int idx = blockIdx.x * 256 + threadIdx.x;
    if (idx >= 64 * TAUG_) return;
    int d = idx / TAUG_, t = idx % TAUG_;
    float v = (t < 129) ? tab[t * 64 + d] : 0.0f;
    bf h = __float2bfloat16(v);
    th[idx] = h;
    tl[idx] = __float2bfloat16(v - __bfloat162float(h));
}

__global__ void build_tabS_kernel(const float* __restrict__ tab,
                                  bf* __restrict__ th, bf* __restrict__ tl) {
    int idx = blockIdx.x * 256 + threadIdx.x;
    if (idx >= TPAD_ * 64) return;
    int t = idx >> 6;
    float v = (t < 129) ? tab[idx] : 0.0f;
    bf h = __float2bfloat16(v);
    th[idx] = h;
    tl[idx] = __float2bfloat16(v - __bfloat162float(h));
}

// ---------------------------------------------------------------------------
__global__ __launch_bounds__(256) void embed_kernel(
    const int* __restrict__ ids, const void* __restrict__ we,
    const void* __restrict__ pe, const void* __restrict__ te,
    float* __restrict__ y, const int* __restrict__ fl) {
    int isbf = *fl;
    int t = blockIdx.x;
    int s = t & (S_ - 1);
    int id = ids[t];
    size_t base = (size_t)t * H_;
    for (int c = threadIdx.x; c < H_; c += 256) {
        y[base + c] = LD(we, (size_t)id * H_ + c, isbf) +
                      LD(pe, (size_t)s * H_ + c, isbf) +
                      LD(te, c, isbf);
    }
}

// ---------------------------------------------------------------------------
__global__ void maskbias_kernel(const int* __restrict__ mask, float* __restrict__ mb) {
    int t = blockIdx.x * 256 + threadIdx.x;
    if (t < BS_) mb[t] = (1.0f - (float)mask[t]) * -10000.0f;
}

// ---------------------------------------------------------------------------
// All layers' fused QKV bias: out[l][0..2303] = [bq|bk|bv][l].
__global__ void biascat_kernel(const void* __restrict__ bq, const void* __restrict__ bk,
                               const void* __restrict__ bv, float* __restrict__ out,
                               const int* __restrict__ fl) {
    int isbf = *fl;
    int t = blockIdx.x * 256 + threadIdx.x;
    if (t >= L_ * 3 * H_) return;
    int l = t / (3 * H_), p = t % (3 * H_);
    const void* s = p < H_ ? bq : (p < 2 * H_ ? bk : bv);
    out[t] = LD(s, (size_t)l * H_ + (p % H_), isbf);
}

// ---------------------------------------------------------------------------
// Barrier-free LayerNorm: 4 waves/block, one row per wave, shuffle reductions.
// out = LN(a (+ a2) (+ resid)) * g + b; optional split-bf16 planes. grid = BS_/4.
__global__ __launch_bounds__(256) void ln_kernel(
    float* out, bf* ohi, bf* olo, const float* a, const float* a2, const float* resid,
    const void* __restrict__ g, const void* __restrict__ b, size_t goff,
    const int* __restrict__ fl) {
    const int isbf = *fl;
    const int lane = threadIdx.x & 63, wv = threadIdx.x >> 6;
    const int row = blockIdx.x * 4 + wv;
    const size_t base = (size_t)row * H_;
    float v[12];
#pragma unroll
    for (int e = 0; e < 12; ++e) {
        const int c = lane + e * 64;
        v[e] = a[base + c];
        if (a2) v[e] += a2[base + c];
        if (resid) v[e] += resid[base + c];
    }
    float s = 0.0f;
#pragma unroll
    for (int e = 0; e < 12; ++e) s += v[e];
    const float mu = wred_sum(s) * (1.0f / (float)H_);
    float q = 0.0f;
#pragma unroll
    for (int e = 0; e < 12; ++e) { v[e] -= mu; q += v[e] * v[e]; }
    const float rs = 1.0f / sqrtf(wred_sum(q) * (1.0f / (float)H_) + 1e-12f);
#pragma unroll
    for (int e = 0; e < 12; ++e) {
        const int c = lane + e * 64;
        float o = v[e] * rs * LD(g, goff + c, isbf) + LD(b, goff + c, isbf);
        out[base + c] = o;
        if (ohi) {
            bf h = __float2bfloat16(o);
            ohi[base + c] = h;
            olo[base + c] = __float2bfloat16(o - __bfloat162float(h));
        }
    }
}

// ---------------------------------------------------------------------------
// Transpose + split weights: W[K,N] -> th,tl bf16 [N,K]. grid (K/32, N/32).
__global__ __launch_bounds__(256) void transpose_split_kernel(
    const void* __restrict__ W, size_t woff, bf* __restrict__ th, bf* __restrict__ tl,
    int K, int N, const int* __restrict__ fl) {
    __shared__ float s[32][33];
    const int isbf = *fl;
    const int tx = threadIdx.x & 31, ty = threadIdx.x >> 5;
    const int k0 = blockIdx.x * 32, n0 = blockIdx.y * 32;
#pragma unroll
    for (int i = 0; i < 4; ++i) {
        int k = k0 + ty + i * 8;
        s[ty + i * 8][tx] = LD(W, woff + (size_t)k * N + (n0 + tx), isbf);
    }
    __syncthreads();
#pragma unroll
    for (int i = 0; i < 4; ++i) {
        int n = n0 + ty + i * 8;
        float v = s[tx][ty + i * 8];
        bf h = __float2bfloat16(v);
        bf l = __float2bfloat16(v - __bfloat162float(h));
        th[(size_t)n * K + k0 + tx] = h;
        tl[(size_t)n * K + k0 + tx] = l;
    }
}

// Merged QKV transpose: grid (24, 24, 3), z selects Wq/Wk/Wv and output slab.
__global__ __launch_bounds__(256) void transpose_split3_kernel(
    const void* __restrict__ W0, const void* __restrict__ W1p, const void* __restrict__ W2p,
    size_t woff, bf* __restrict__ th, bf* __restrict__ tl, const int* __restrict__ fl) {
    __shared__ float s[32][33];
    const int isbf = *fl;
    const void* W = blockIdx.z == 0 ? W0 : (blockIdx.z == 1 ? W1p : W2p);
    bf* tho = th + (size_t)blockIdx.z * H_ * H_;
    bf* tlo = tl + (size_t)blockIdx.z * H_ * H_;
    const int tx = threadIdx.x & 31, ty = threadIdx.x >> 5;
    const int k0 = blockIdx.x * 32, n0 = blockIdx.y * 32;
#pragma unroll
    for (int i = 0; i < 4; ++i) {
        int k = k0 + ty + i * 8;
        s[ty + i * 8][tx] = LD(W, woff + (size_t)k * H_ + (n0 + tx), isbf);
    }
    __syncthreads();
#pragma unroll
    for (int i = 0; i < 4; ++i) {
        int n = n0 + ty + i * 8;
        float v = s[tx][ty + i * 8];
        bf h = __float2bfloat16(v);
        bf l = __float2bfloat16(v - __bfloat162float(h));
        tho[(size_t)n * H_ + k0 + tx] = h;
        tlo[(size_t)n * H_ + k0 + tx] = l;
    }
}

// ---------------------------------------------------------------------------
// Split-bf16 MFMA GEMM (3 products): C[M,N] = (Ah+Al)[M,K-slice] @ (Bh+Bl)^T.
// 128x128 tile, BK=32, 4 waves. blockIdx.z = K-split index (partials to C / C2).
// XCD-chunked bijective block swizzle (all grids have nwg % 8 == 0).
template<int MR>
__global__ __launch_bounds__(256, 2) void mgemm_kernel(
    const bf* __restrict__ Ah, const bf* __restrict__ Al,
    const bf* __restrict__ Bh, const bf* __restrict__ Bl,
    const void* __restrict__ bias, size_t boff,
    float* __restrict__ C, float* __restrict__ C2,
    bf* __restrict__ Chi, bf* __restrict__ Clo,
    int N, int K, int lda, int ldb, int act, int split_out, const int* __restrict__ fl) {
    __shared__ __align__(16) unsigned short Ahs[MR * 32][32];
    __shared__ __align__(16) unsigned short Als[MR * 32][32];
    __shared__ __align__(16) unsigned short Bhs[128][32];
    __shared__ __align__(16) unsigned short Bls[128][32];
    const int gx = gridDim.x, gy = gridDim.y, gz = gridDim.z;
    const int nwg = gx * gy * gz;
    const int flat = (blockIdx.z * gy + blockIdx.y) * gx + blockIdx.x;
    const int swz = (flat & 7) * (nwg >> 3) + (flat >> 3);
    const int bx = swz % gx;
    const int by = (swz / gx) % gy;
    const int bz = swz / (gx * gy);

    const int tid  = threadIdx.x;
    const int lane = tid & 63;
    const int wid  = tid >> 6;
    const int wr   = wid >> 1, wc = wid & 1;
    const int m0 = by * (MR * 32), n0 = bx * 128;
    const size_t koff = (size_t)bz * K;
    const int srow = lane >> 2;
    const int scol = (lane & 3) * 8;

    const fx4 fzero = {0.f, 0.f, 0.f, 0.f};
    fx4 acc[MR][4];
#pragma unroll
    for (int i = 0; i < MR; ++i)
#pragma unroll
        for (int j = 0; j < 4; ++j) acc[i][j] = fzero;

    for (int k0 = 0; k0 < K; k0 += 32) {
#pragma unroll
        for (int t = 0; t < MR / 2; ++t) {
            const int r = wid * (MR * 8) + t * 16;
            const size_t ga = (size_t)(m0 + r + srow) * lda + koff + k0 + scol;
            gload16(Ah + ga, &Ahs[r][0]);
            gload16(Al + ga, &Als[r][0]);
        }
#pragma unroll
        for (int t = 0; t < 2; ++t) {
            const int r = wid * 32 + t * 16;
            const size_t gb = (size_t)(n0 + r + srow) * ldb + koff + k0 + scol;
            gload16(Bh + gb, &Bhs[r][0]);
            gload16(Bl + gb, &Bls[r][0]);
        }
        __syncthreads();

        const int fr = lane & 15;
        const int ko = (lane >> 4) * 8;
        s16x8 ah[MR], al[MR], bh[4], bl[4];
#pragma unroll
        for (int f = 0; f < MR; ++f) {
            ah[f] = *(const s16x8*)&Ahs[wr * (MR * 16) + f * 16 + fr][ko];
            al[f] = *(const s16x8*)&Als[wr * (MR * 16) + f * 16 + fr][ko];
        }
#pragma unroll
        for (int f = 0; f < 4; ++f) {
            bh[f] = *(const s16x8*)&Bhs[wc * 64 + f * 16 + fr][ko];
            bl[f] = *(const s16x8*)&Bls[wc * 64 + f * 16 + fr][ko];
        }
#pragma unroll
        for (int im = 0; im < MR; ++im)
#pragma unroll
            for (int in = 0; in < 4; ++in) {
                acc[im][in] = __builtin_amdgcn_mfma_f32_16x16x32_bf16(ah[im], bh[in], acc[im][in], 0, 0, 0);
                acc[im][in] = __builtin_amdgcn_mfma_f32_16x16x32_bf16(ah[im], bl[in], acc[im][in], 0, 0, 0);
                acc[im][in] = __builtin_amdgcn_mfma_f32_16x16x32_bf16(al[im], bh[in], acc[im][in], 0, 0, 0);
            }
        __syncthreads();
    }

    const int isbf = *fl;
    float* Co = (bz == 0) ? C : C2;
    const int cr0 = m0 + wr * (MR * 16) + (lane >> 4) * 4;
    const int cc0 = n0 + wc * 64 + (lane & 15);
#pragma unroll
    for (int in = 0; in < 4; ++in) {
        const int col = cc0 + in * 16;
        const float bv = (bz == 0) ? LD(bias, boff + col, isbf) : 0.0f;
#pragma unroll
        for (int im = 0; im < MR; ++im) {
#pragma unroll
            for (int r = 0; r < 4; ++r) {
                const int row = cr0 + im * 16 + r;
                float v = acc[im][in][r] + bv;
                if (act) v = 0.5f * v * (1.0f + erff(v * 0.70710678118654752f));
                if (split_out) {
                    bf h = __float2bfloat16(v);
                    bf l = __float2bfloat16(v - __bfloat162float(h));
                    Chi[(size_t)row * N + col] = h;
                    Clo[(size_t)row * N + col] = l;
                } else {
                    Co[(size_t)row * N + col] = v;
                }
            }
        }
    }
}

// ---------------------------------------------------------------------------
// qrel[bb,h,i,t] = q . tab[t]  (3-product MFMA). grid (CB*S/128, NH, 3).
__global__ __launch_bounds__(256) void qrel_kernel(
    const bf* __restrict__ qh, const bf* __restrict__ ql,
    const bf* __restrict__ tabSh, const bf* __restrict__ tabSl,
    float* __restrict__ qrel, int astr, int b0) {
    const int tid = threadIdx.x, lane = tid & 63, wv = tid >> 6;
    const int rbase = blockIdx.x * 128;
    const int h = blockIdx.y;
    const int t0 = blockIdx.z * 48;
    const int fr = lane & 15, ko = (lane >> 4) * 8;
    const fx4 fz = {0.f, 0.f, 0.f, 0.f};
    fx4 acc[2][3];
#pragma unroll
    for (int m = 0; m < 2; ++m)
#pragma unroll
        for (int n = 0; n < 3; ++n) acc[m][n] = fz;
#pragma unroll
    for (int ks = 0; ks < 2; ++ks) {
        s16x8 a_h[2], a_l[2], b_h[3], b_l[3];
#pragma unroll
        for (int m = 0; m < 2; ++m) {
            const int row = rbase + wv * 32 + m * 16 + fr;
            const size_t ga = ((size_t)(b0 * S_) + row) * astr + h * 64 + ks * 32 + ko;
            a_h[m] = *(const s16x8*)(qh + ga);
            a_l[m] = *(const s16x8*)(ql + ga);
        }
#pragma unroll
        for (int n = 0; n < 3; ++n) {
            const int trow = t0 + n * 16 + fr;
            const size_t gb = (size_t)trow * 64 + ks * 32 + ko;
            b_h[n] = *(const s16x8*)(tabSh + gb);
            b_l[n] = *(const s16x8*)(tabSl + gb);
        }
#pragma unroll
        for (int m = 0; m < 2; ++m)
#pragma unroll
            for (int n = 0; n < 3; ++n) {
                acc[m][n] = __builtin_amdgcn_mfma_f32_16x16x32_bf16(a_h[m], b_h[n], acc[m][n], 0, 0, 0);
                acc[m][n] = __builtin_amdgcn_mfma_f32_16x16x32_bf16(a_h[m], b_l[n], acc[m][n], 0, 0, 0);
                acc[m][n] = __builtin_amdgcn_mfma_f32_16x16x32_bf16(a_l[m], b_h[n], acc[m][n], 0, 0, 0);
            }
    }
    const int rr = (lane >> 4) * 4, cc = lane & 15;
#pragma unroll
    for (int m = 0; m < 2; ++m)
#pragma unroll
        for (int n = 0; n < 3; ++n)
#pragma unroll
            for (int r = 0; r < 4; ++r) {
                const int row = rbase + wv * 32 + m * 16 + rr + r;
                const int t = t0 + n * 16 + cc;
                const int bb = row >> 9, ii = row & (S_ - 1);
                qrel[(((size_t)bb * NH_ + h) * S_ + ii) * TPAD_ + t] = acc[m][n][r];
            }
}

// ---------------------------------------------------------------------------
// Fused QK^T + rel/mask/scale + softmax + augmented-P emit.
// grid (S/128, NH, CB), 512 threads (8 waves). Wave w: row-group w>>1 (32 rows),
// col-half w&1 (256 cols). K tile (512x64, hi+lo) in 128 KB dynamic LDS; after
// MFMA the same LDS holds the P tile [128][512] for coalesced copy-out.
__global__ __launch_bounds__(512, 1) void qksm_kernel(
    const bf* __restrict__ qh, const bf* __restrict__ ql,
    const bf* __restrict__ kh, const bf* __restrict__ kl,
    const float* __restrict__ qrel, const float* __restrict__ mb,
    bf* __restrict__ pah, bf* __restrict__ pal, int astr, int b0) {
    extern __shared__ __align__(16) char smem[];
    unsigned short (*Kh_)[64] = (unsigned short(*)[64])smem;             // [512][64]
    unsigned short (*Kl_)[64] = (unsigned short(*)[64])(smem + 65536);   // [512][64]
    unsigned short (*P_)[512] = (unsigned short(*)[512])smem;            // [128][512]
    __shared__ float st_m[2][128], st_s[2][128], st_lo[2][128], st_hi[2][128];

    const int tid = threadIdx.x, lane = tid & 63, wv = tid >> 6;
    const int i0 = blockIdx.x * 128, h = blockIdx.y, bb = blockIdx.z;
    const int b = b0 + bb;
    const int rg = wv >> 1, hf = wv & 1;

    // ---- stage K (both planes), chunk-XOR swizzled ----
    const int srow = lane >> 3, schunk = (lane & 7) ^ (srow & 7);
#pragma unroll
    for (int t = 0; t < 8; ++t) {
        const int r = wv * 64 + t * 8;
        const size_t ga = (size_t)(b * S_ + r + srow) * astr + h * 64 + schunk * 8;
        gload16(kh + ga, &Kh_[r][0]);
        gload16(kl + ga, &Kl_[r][0]);
    }
    // ---- Q fragments direct from global ----
    const int fr = lane & 15, gq = lane >> 4;
    s16x8 a_h[2][2], a_l[2][2];   // [mm][ks]
#pragma unroll
    for (int mm = 0; mm < 2; ++mm)
#pragma unroll
        for (int ks = 0; ks < 2; ++ks) {
            const size_t ga = (size_t)(b * S_ + i0 + rg * 32 + mm * 16 + fr) * astr
                            + h * 64 + ks * 32 + gq * 8;
            a_h[mm][ks] = *(const s16x8*)(qh + ga);
            a_l[mm][ks] = *(const s16x8*)(ql + ga);
        }
    __syncthreads();

    // ---- MFMA: wave covers 32 rows x 256 cols ----
    const fx4 fz = {0.f, 0.f, 0.f, 0.f};
    fx4 acc[2][16];
#pragma unroll
    for (int m = 0; m < 2; ++m)
#pragma unroll
        for (int n = 0; n < 16; ++n) acc[m][n] = fz;
#pragma unroll
    for (int nn = 0; nn < 16; ++nn) {
        const int jrow = hf * 256 + nn * 16 + fr;
#pragma unroll
        for (int ks = 0; ks < 2; ++ks) {
            const s16x8 b_h = ldfrag64(&Kh_[0][0], jrow, ks * 4 + gq);
            const s16x8 b_l = ldfrag64(&Kl_[0][0], jrow, ks * 4 + gq);
#pragma unroll
            for (int mm = 0; mm < 2; ++mm) {
                acc[mm][nn] = __builtin_amdgcn_mfma_f32_16x16x32_bf16(a_h[mm][ks], b_h, acc[mm][nn], 0, 0, 0);
                acc[mm][nn] = __builtin_amdgcn_mfma_f32_16x16x32_bf16(a_h[mm][ks], b_l, acc[mm][nn], 0, 0, 0);
                acc[mm][nn] = __builtin_amdgcn_mfma_f32_16x16x32_bf16(a_l[mm][ks], b_h, acc[mm][nn], 0, 0, 0);
            }
        }
    }

    // ---- rel/mask/scale + wave-local softmax stats (per-half) ----
    const int c = lane & 15;
    float m_w[2][4];
#pragma unroll
    for (int mm = 0; mm < 2; ++mm) {
#pragma unroll
        for (int r = 0; r < 4; ++r) {
            const int row_l = rg * 32 + mm * 16 + gq * 4 + r;
            const int ig = i0 + row_l;
            const size_t qb = (((size_t)bb * NH_ + h) * S_ + ig) * TPAD_;
            const float q0 = qrel[qb], q128 = qrel[qb + 128];
            float mx = -1e30f;
#pragma unroll
            for (int nn = 0; nn < 16; ++nn) {
                const int j = hf * 256 + nn * 16 + c;
                const int d = j - ig;
                const float qr = d <= -64 ? q0 : (d >= 64 ? q128 : qrel[qb + d + 64]);
                const float v = (acc[mm][nn][r] + qr) * 0.125f + mb[b * S_ + j];
                acc[mm][nn][r] = v;
                mx = fmaxf(mx, v);
            }
            mx = gred_max(mx);
            float sm = 0.0f, sl = 0.0f, sh = 0.0f;
#pragma unroll
            for (int nn = 0; nn < 16; ++nn) {
                const int j = hf * 256 + nn * 16 + c;
                const int d = j - ig;
                const float e = expf(acc[mm][nn][r] - mx);
                acc[mm][nn][r] = e;
                sm += e;
                if (d <= -64) sl += e;
                else if (d >= 64) sh += e;
            }
            sm = gred_sum(sm); sl = gred_sum(sl); sh = gred_sum(sh);
            m_w[mm][r] = mx;
            if (c == 0) {
                st_m[hf][row_l] = mx;
                st_s[hf][row_l] = sm;
                st_lo[hf][row_l] = sl;
                st_hi[hf][row_l] = sh;
            }
        }
    }
    __syncthreads();   // stats ready; all waves done reading K LDS

    const size_t obase = ((size_t)bb * NH_ + h) * S_ + i0;
    // plane pass: 0 = hi, 1 = lo
#pragma unroll
    for (int plane = 0; plane < 2; ++plane) {
        // owners write this plane of P into LDS
#pragma unroll
        for (int mm = 0; mm < 2; ++mm)
#pragma unroll
            for (int r = 0; r < 4; ++r) {
                const int row_l = rg * 32 + mm * 16 + gq * 4 + r;
                const float m0 = st_m[0][row_l], m1 = st_m[1][row_l];
                const float M = fmaxf(m0, m1);
                const float inv = 1.0f /
                    (st_s[0][row_l] * expf(m0 - M) + st_s[1][row_l] * expf(m1 - M));
                const float f = expf(m_w[mm][r] - M) * inv;
#pragma unroll
                for (int nn = 0; nn < 16; ++nn) {
                    const int col = hf * 256 + nn * 16 + c;
                    const float p = acc[mm][nn][r] * f;
                    bf hb = __float2bfloat16(p);
                    if (plane == 0) {
                        P_[row_l][col] = *(unsigned short*)&hb;
                    } else {
                        const float lo = p - __bfloat162float(hb);
                        bf lb = __float2bfloat16(lo);
                        P_[row_l][col] = *(unsigned short*)&lb;
                    }
                }
            }
        __syncthreads();
        bf* dst = plane == 0 ? pah : pal;
        // main region: coalesced copy-out
#pragma unroll
        for (int p = 0; p < 16; ++p) {
            const int idx = tid + p * 512;
            const int row = idx >> 6, ch = idx & 63;
            const s16x8 v = *(const s16x8*)&P_[row][ch * 8];
            *(s16x8*)((unsigned short*)dst + (obase + row) * KAUG_ + ch * 8) = v;
        }
        // aug region: 128 rows x 160 cols
#pragma unroll
        for (int p = 0; p < 5; ++p) {
            const int idx = tid + p * 512;
            const int row = idx / 20, ach = idx % 20;
            const float m0 = st_m[0][row], m1 = st_m[1][row];
            const float M = fmaxf(m0, m1);
            const float e0 = expf(m0 - M), e1 = expf(m1 - M);
            const float inv = 1.0f / (st_s[0][row] * e0 + st_s[1][row] * e1);
            unsigned short o[8] __attribute__((aligned(16)));
#pragma unroll
            for (int cc = 0; cc < 8; ++cc) {
                const int t = ach * 8 + cc;
                float v = 0.0f;
                bool direct = false;
                unsigned short dv = 0;
                if (t == 0)        v = (st_lo[0][row] * e0 + st_lo[1][row] * e1) * inv;
                else if (t == 128) v = (st_hi[0][row] * e0 + st_hi[1][row] * e1) * inv;
                else if (t < 128) {
                    const int c2 = i0 + row + t - 64;
                    if (c2 >= 0 && c2 < 512) { dv = P_[row][c2]; direct = true; }
                }
                if (direct) o[cc] = dv;
                else {
                    bf hb = __float2bfloat16(v);
                    if (plane == 0) o[cc] = *(unsigned short*)&hb;
                    else {
                        const float lo = v - __bfloat162float(hb);
                        bf lb = __float2bfloat16(lo);
                        o[cc] = *(unsigned short*)&lb;
                    }
                }
            }
            *(s16x8*)((unsigned short*)dst + (obase + row) * KAUG_ + 512 + ach * 8) =
                *(const s16x8*)o;
        }
        __syncthreads();
    }
}

// ---------------------------------------------------------------------------
// Build augmented V^T: vaug[bb][h][d][0..511]=V^T, [512..671]=tabT.
// grid (NH, 2, CB). v planes have row stride astr.
__global__ __launch_bounds__(256) void vaug_kernel(
    const bf* __restrict__ vh, const bf* __restrict__ vl,
    const bf* __restrict__ tabTh, const bf* __restrict__ tabTl,
    bf* __restrict__ vah, bf* __restrict__ val_, int astr, int b0) {
    __shared__ unsigned short tile[64][71];
    const int h = blockIdx.x, pl = blockIdx.y, bb = blockIdx.z;
    const int b = b0 + bb;
    const bf* src  = pl ? vl : vh;
    bf*       dst  = pl ? val_ : vah;
    const bf* tsrc = pl ? tabTl : tabTh;
    const int tid = threadIdx.x;
    const size_t dbase = ((size_t)bb * NH_ + h) * 64;
    for (int j0 = 0; j0 < S_; j0 += 64) {
        for (int idx = tid; idx < 4096; idx += 256) {
            int jj = idx >> 6, d = idx & 63;
            tile[jj][d] = *(const unsigned short*)&src[(size_t)(b * S_ + j0 + jj) * astr + h * 64 + d];
        }
        __syncthreads();
        for (int idx = tid; idx < 4096; idx += 256) {
            int d = idx >> 6, jj = idx & 63;
            *(unsigned short*)&dst[(dbase + d) * KAUG_ + j0 + jj] = tile[jj][d];
        }
        __syncthreads();
    }
    for (int idx = tid; idx < 64 * TAUG_; idx += 256) {
        int d = idx / TAUG_, t = idx % TAUG_;
        *(unsigned short*)&dst[(dbase + d) * KAUG_ + 512 + t] =
            *(const unsigned short*)&tsrc[idx];
    }
}

// ---------------------------------------------------------------------------
// ctx = [P|arel] @ [V; tab]: grid (NH, 4, CB). M=128, N=64, K=672.
__global__ __launch_bounds__(256, 2) void pv_kernel(
    const bf* __restrict__ pah, const bf* __restrict__ pal,
    const bf* __restrict__ vah, const bf* __restrict__ val_,
    bf* __restrict__ ch, bf* __restrict__ cl, int b0) {
    __shared__ __align__(16) unsigned short Ah[128][32];
    __shared__ __align__(16) unsigned short Al[128][32];
    __shared__ __align__(16) unsigned short Bh[64][32];
    __shared__ __align__(16) unsigned short Bl[64][32];
    const int tid = threadIdx.x, lane = tid & 63, wv = tid >> 6;
    const int h = blockIdx.x, i0 = blockIdx.y * 128, bb = blockIdx.z;
    const int b = b0 + bb;
    const int srow = lane >> 2;
    const int schunk = (lane & 3) ^ (srow & 3);
    const fx4 fz = {0.f, 0.f, 0.f, 0.f};
    fx4 acc[2][4];
#pragma unroll
    for (int m = 0; m < 2; ++m)
#pragma unroll
        for (int n = 0; n < 4; ++n) acc[m][n] = fz;

    for (int k0 = 0; k0 < KAUG_; k0 += 32) {
#pragma unroll
        for (int t = 0; t < 2; ++t) {
            const int r = wv * 32 + t * 16;
            const size_t ga = (((size_t)bb * NH_ + h) * S_ + i0 + r + srow) * KAUG_ + k0 + schunk * 8;
            gload16(pah + ga, &Ah[r][0]);
            gload16(pal + ga, &Al[r][0]);
        }
        {
            const int r = wv * 16;
            const size_t gb = (((size_t)bb * NH_ + h) * 64 + r + srow) * KAUG_ + k0 + schunk * 8;
            gload16(vah + gb, &Bh[r][0]);
            gload16(val_ + gb, &Bl[r][0]);
        }
        __syncthreads();
        const int fr = lane & 15, g = lane >> 4;
        s16x8 a_h[2], a_l[2], b_h[4], b_l[4];
#pragma unroll
        for (int m = 0; m < 2; ++m) {
            const int row = wv * 32 + m * 16 + fr;
            a_h[m] = ldfrag32(&Ah[0][0], row, g);
            a_l[m] = ldfrag32(&Al[0][0], row, g);
        }
#pragma unroll
        for (int n = 0; n < 4; ++n) {
            const int row = n * 16 + fr;
            b_h[n] = ldfrag32(&Bh[0][0], row, g);
            b_l[n] = ldfrag32(&Bl[0][0], row, g);
        }
#pragma unroll
        for (int m = 0; m < 2; ++m)
#pragma unroll
            for (int n = 0; n < 4; ++n) {
                acc[m][n] = __builtin_amdgcn_mfma_f32_16x16x32_bf16(a_h[m], b_h[n], acc[m][n], 0, 0, 0);
                acc[m][n] = __builtin_amdgcn_mfma_f32_16x16x32_bf16(a_h[m], b_l[n], acc[m][n], 0, 0, 0);
                acc[m][n] = __builtin_amdgcn_mfma_f32_16x16x32_bf16(a_l[m], b_h[n], acc[m][n], 0, 0, 0);
            }
        __syncthreads();
    }
    const int rr = (lane >> 4) * 4, cc = lane & 15;
#pragma unroll
    for (int m = 0; m < 2; ++m)
#pragma unroll
        for (int n = 0; n < 4; ++n)
#pragma unroll
            for (int r = 0; r < 4; ++r) {
                const int row = i0 + wv * 32 + m * 16 + rr + r;
                const int d = n * 16 + cc;
                const float v = acc[m][n][r];
                bf hh = __float2bfloat16(v);
                const size_t o = (size_t)(b * S_ + row) * H_ + h * 64 + d;
                ch[o] = hh;
                cl[o] = __float2bfloat16(v - __bfloat162float(hh));
            }
}

// ---------------------------------------------------------------------------
__global__ __launch_bounds__(256) void pool_kernel(
    const float* __restrict__ x, const void* __restrict__ pW,
    const void* __restrict__ pb, float* __restrict__ pooled,
    const int* __restrict__ fl) {
    int isbf = *fl;
    int b = blockIdx.x;
    const float* xr = x + (size_t)b * S_ * H_;
    for (int n = threadIdx.x; n < H_; n += 256) {
        float acc = LD(pb, n, isbf);
        for (int kx = 0; kx < H_; ++kx)
            acc += xr[kx] * LD(pW, (size_t)kx * H_ + n, isbf);
        pooled[b * H_ + n] = tanhf(acc);
    }
}

__global__ __launch_bounds__(256) void seqavg_kernel(
    const float* __restrict__ x, float* __restrict__ sa) {
    int b = blockIdx.x;
    for (int c = threadIdx.x; c < H_; c += 256) {
        float s = 0.0f;
        for (int j = 0; j < S_; ++j) s += x[((size_t)b * S_ + j) * H_ + c];
        sa[b * H_ + c] = s * (1.0f / (float)S_);
    }
}

__global__ void head_kernel(const float* __restrict__ sa, const float* __restrict__ pooled,
                            const void* __restrict__ cW, const void* __restrict__ cb,
                            void* __restrict__ out, const int* __restrict__ fl) {
    int isbf = *fl;
    int t = threadIdx.x;
    if (t >= B_ * NC_) return;
    int b = t / NC_, c = t % NC_;
    float acc = LD(cb, c, isbf);
    for (int kx = 0; kx < H_; ++kx)
        acc += sa[b * H_ + kx] * LD(cW, (size_t)kx * NC_ + c, isbf);
    for (int kx = 0; kx < H_; ++kx)
        acc += pooled[b * H_ + kx] * LD(cW, (size_t)(H_ + kx) * NC_ + c, isbf);
    if (isbf) ((bf*)out)[t] = __float2bfloat16(acc);
    else      ((float*)out)[t] = acc;
}

// ---------------------------------------------------------------------------
extern "C" void kernel_launch(void* const* d_in, const int* in_sizes, int n_in,
                              void* d_out, int out_size, void* d_ws, size_t ws_size,
                              hipStream_t stream) {
    (void)in_sizes; (void)n_in; (void)out_size;
    const int* ids   = (const int*)d_in[0];
    const int* amask = (const int*)d_in[1];
    const void* we  = d_in[2];
    const void* pe  = d_in[3];
    const void* te  = d_in[4];
    const void* lng = d_in[5];
    const void* lnb = d_in[6];
    const void* Wq  = d_in[7];
    const void* bq  = d_in[8];
    const void* Wk  = d_in[9];
    const void* bk  = d_in[10];
    const void* Wv  = d_in[11];
    const void* bv  = d_in[12];
    const void* Wo  = d_in[13];
    const void* bo  = d_in[14];
    const void* l1g = d_in[15];
    const void* l1b = d_in[16];
    const void* W1  = d_in[17];
    const void* b1  = d_in[18];
    const void* W2  = d_in[19];
    const void* b2  = d_in[20];
    const void* l2g = d_in[21];
    const void* l2b = d_in[22];
    const void* pW  = d_in[23];
    const void* pb  = d_in[24];
    const void* cW  = d_in[25];
    const void* cb  = d_in[26];

    // ---- workspace carve (runtime CB selection from ws_size) ----
    char* cur = (char*)d_ws;
    auto alloc = [&](size_t bytes) -> char* {
        char* p = cur;
        cur += (bytes + 255) & ~(size_t)255;
        return p;
    };
    float* x    = (float*)alloc(BSH_ * 4);
    float* r0   = (float*)alloc(BSH_ * 4);   // ctx split planes; FFN hidden hi spans r0+r1f
    float* r1f  = (float*)alloc(BSH_ * 4);   // qkv planes span r1f..r3f
    float* r2f  = (float*)alloc(BSH_ * 4);   // FFN hidden lo spans r2f+r3f
    float* r3f  = (float*)alloc(BSH_ * 4);
    float* z    = (float*)alloc(BSH_ * 4);   // split-K partial 0
    float* z2   = (float*)alloc(BSH_ * 4);   // split-K partial 1
    float* tab  = (float*)alloc(129 * 64 * 4);
    float* mb   = (float*)alloc(BS_ * 4);
    float* pool = (float*)alloc(B_ * H_ * 4);
    float* sa   = (float*)alloc(B_ * H_ * 4);
    float* bqkv = (float*)alloc((size_t)L_ * 3 * H_ * 4);
    bf* tabTh   = (bf*)alloc(64 * TAUG_ * 2);
    bf* tabTl   = (bf*)alloc(64 * TAUG_ * 2);
    bf* tabSh   = (bf*)alloc(TPAD_ * 64 * 2);
    bf* tabSl   = (bf*)alloc(TPAD_ * 64 * 2);
    int* flag   = (int*)alloc(256);
    int* zflag  = flag + 1;

    const size_t fixed = (size_t)(cur - (char*)d_ws);
    auto regA_sz = [&](int CB) {  // wth/wtl  U  qrel
        size_t wt = (size_t)2 * H_ * FF_ * 2;
        size_t qr = (size_t)CB * NH_ * S_ * TPAD_ * 4;
        return (wt > qr ? wt : qr);
    };
    const size_t regB_bytes = (size_t)4 * BSH_;   // xh/xl split planes
    auto need = [&](int CB) {
        return fixed + regA_sz(CB) + regB_bytes
             + (size_t)CB * NH_ * S_ * KAUG_ * 2 * 2      // pah+pal
             + (size_t)CB * NH_ * 64 * KAUG_ * 2 * 2      // vah+val
             + 4096;
    };
    int CB = 8;
    while (CB > 1 && need(CB) > ws_size) CB >>= 1;

    char* regA = alloc(regA_sz(CB));
    char* regB = alloc(regB_bytes);
    bf* pah  = (bf*)alloc((size_t)CB * NH_ * S_ * KAUG_ * 2 * 2);
    bf* pal  = pah + (size_t)CB * NH_ * S_ * KAUG_;
    bf* vah  = (bf*)alloc((size_t)CB * NH_ * 64 * KAUG_ * 2 * 2);
    bf* val_ = vah + (size_t)CB * NH_ * 64 * KAUG_;

    bf*    wth   = (bf*)regA;                 // transposed weights (stacked for QKV)
    bf*    wtl   = wth + (size_t)H_ * FF_;
    float* qrelb = (float*)regA;
    bf*    xh    = (bf*)regB;
    bf*    xl    = xh + BSH_;

    bf* qkvh = (bf*)r1f;                      // [4096][2304] hi plane (spans r1f..r3f)
    bf* qkvl = qkvh + (size_t)BS_ * QSTR_;
    bf* ch   = (bf*)r0;  bf* cl = ch + BSH_;  // pv context planes
    bf* hbh  = (bf*)r0;                       // FFN hidden hi spans r0+r1f
    bf* hbl  = (bf*)r2f;                      // FFN hidden lo spans r2f+r3f

    detect_kernel<<<1, 64, 0, stream>>>((const unsigned int*)lng, flag);
    build_table_kernel<<<(129 * 64 + 255) / 256, 256, 0, stream>>>(tab);
    build_tabT_kernel<<<(64 * TAUG_ + 255) / 256, 256, 0, stream>>>(tab, tabTh, tabTl);
    build_tabS_kernel<<<(TPAD_ * 64 + 255) / 256, 256, 0, stream>>>(tab, tabSh, tabSl);
    maskbias_kernel<<<(BS_ + 255) / 256, 256, 0, stream>>>(amask, mb);
    biascat_kernel<<<(L_ * 3 * H_ + 255) / 256, 256, 0, stream>>>(bq, bk, bv, bqkv, flag);
    embed_kernel<<<BS_, 256, 0, stream>>>(ids, we, pe, te, r0, flag);
    ln_kernel<<<BS_ / 4, 256, 0, stream>>>(x, xh, xl, r0, nullptr, nullptr, lng, lnb, 0, flag);

    dim3 tp3(H_ / 32, H_ / 32, 3);
    dim3 tpHH(H_ / 32, H_ / 32);
    dim3 tpHF(H_ / 32, FF_ / 32);
    dim3 tpFH(FF_ / 32, H_ / 32);
    dim3 gQKV(3 * H_ / 128, BS_ / 128, 1);    // 576 blocks
    dim3 gSK(H_ / 128, BS_ / 128, 2);         // 384 blocks, split-K
    dim3 gF(FF_ / 128, BS_ / 128, 1);         // 768 blocks
    dim3 gQR(CB * S_ / 128, NH_, 3);
    dim3 gVA(NH_, 2, CB);
    dim3 gQS(S_ / 128, NH_, CB);
    dim3 gPV(NH_, 4, CB);

    for (int l = 0; l < L_; ++l) {
        const size_t oHH = (size_t)l * H_ * H_;
        const size_t oH  = (size_t)l * H_;
        const size_t oHF = (size_t)l * H_ * FF_;
        const size_t oF  = (size_t)l * FF_;

        // ---- fused QKV GEMM: N = 2304, stacked transposed weights ----
        transpose_split3_kernel<<<tp3, 256, 0, stream>>>(Wq, Wk, Wv, oHH, wth, wtl, flag);
        mgemm_kernel<4><<<gQKV, 256, 0, stream>>>(xh, xl, wth, wtl,
            bqkv, (size_t)l * 3 * H_, nullptr, nullptr, qkvh, qkvl,
            QSTR_, H_, H_, H_, 0, 1, zflag);

        // ---- attention, chunked by CB batches ----
        for (int b0 = 0; b0 < B_; b0 += CB) {
            qrel_kernel<<<gQR, 256, 0, stream>>>(qkvh, qkvl, tabSh, tabSl, qrelb, QSTR_, b0);
            vaug_kernel<<<gVA, 256, 0, stream>>>(qkvh + 2 * H_, qkvl + 2 * H_,
                tabTh, tabTl, vah, val_, QSTR_, b0);
            qksm_kernel<<<gQS, 512, 131072, stream>>>(qkvh, qkvl, qkvh + H_, qkvl + H_,
                qrelb, mb, pah, pal, QSTR_, b0);
            pv_kernel<<<gPV, 256, 0, stream>>>(pah, pal, vah, val_, ch, cl, b0);
        }

        // ---- output projection (split-K=2) + LN1 ----
        transpose_split_kernel<<<tpHH, 256, 0, stream>>>(Wo, oHH, wth, wtl, H_, H_, flag);
        mgemm_kernel<4><<<gSK, 256, 0, stream>>>(ch, cl, wth, wtl, bo, oH,
            z, z2, nullptr, nullptr, H_, H_ / 2, H_, H_, 0, 0, flag);
        ln_kernel<<<BS_ / 4, 256, 0, stream>>>(x, xh, xl, z, z2, x, l1g, l1b, oH, flag);

        // ---- FFN ----
        transpose_split_kernel<<<tpHF, 256, 0, stream>>>(W1, oHF, wth, wtl, H_, FF_, flag);
        mgemm_kernel<4><<<gF, 256, 0, stream>>>(xh, xl, wth, wtl, b1, oF,
            nullptr, nullptr, hbh, hbl, FF_, H_, H_, H_, 1, 1, flag);
        transpose_split_kernel<<<tpFH, 256, 0, stream>>>(W2, oHF, wth, wtl, FF_, H_, flag);
        mgemm_kernel<4><<<gSK, 256, 0, stream>>>(hbh, hbl, wth, wtl, b2, oH,
            z, z2, nullptr, nullptr, H_, FF_ / 2, FF_, FF_, 0, 0, flag);
        ln_kernel<<<BS_ / 4, 256, 0, stream>>>(x, xh, xl, z, z2, x, l2g, l2b, oH, flag);
    }

    pool_kernel<<<B_, 256, 0, stream>>>(x, pW, pb, pool, flag);
    seqavg_kernel<<<B_, 256, 0, stream>>>(x, sa);
    head_kernel<<<1, 64, 0, stream>>>(sa, pool, cW, cb, d_out, flag);
}